// Round 12
// baseline (414.035 us; speedup 1.0000x reference)
//
#include <hip/hip_runtime.h>
#include <hip/hip_bf16.h>

#define BATCH 4
#define SEQ   2048
#define DIM   1024
#define HEADS 16
#define DHEAD 64
#define INNER 1024   // HEADS*DHEAD
#define QKV_N 3072   // 3*INNER
#define MTOT  8192   // BATCH*SEQ

typedef short bf16x8 __attribute__((ext_vector_type(8)));
typedef float f32x4  __attribute__((ext_vector_type(4)));
#define MFMA16(a,b,c) __builtin_amdgcn_mfma_f32_16x16x32_bf16((a),(b),(c),0,0,0)

// log2(e) * dhead^-0.5  (scale folded into Q so softmax can use native exp2)
#define QSCALE 0.1803368801111204f

static __device__ __forceinline__ unsigned fau(float f) { return __float_as_uint(f); }
static __device__ __forceinline__ float max3f(float a, float b, float c) {
    return fmaxf(fmaxf(a, b), c);   // clang fuses to v_max3_f32
}

// Truncate-to-bf16 pack of 4 floats (hi plane). Packs 4 bf16 into uint2.
static __device__ __forceinline__ uint2 pack_hi4(float4 v) {
    return make_uint2((fau(v.x) >> 16) | (fau(v.y) & 0xffff0000u),
                      (fau(v.z) >> 16) | (fau(v.w) & 0xffff0000u));
}
static __device__ __forceinline__ float4 resid4(float4 v) {
    float4 r;
    r.x = v.x - __uint_as_float(fau(v.x) & 0xffff0000u);
    r.y = v.y - __uint_as_float(fau(v.y) & 0xffff0000u);
    r.z = v.z - __uint_as_float(fau(v.z) & 0xffff0000u);
    r.w = v.w - __uint_as_float(fau(v.w) & 0xffff0000u);
    return r;
}
static __device__ __forceinline__ uint2 pack_lo4(float4 v) { return pack_hi4(resid4(v)); }

// Packed RNE fp32->bf16 pair: dst[15:0]=bf16(a), dst[31:16]=bf16(b).
static __device__ __forceinline__ unsigned cvt_pk_bf16(float a, float b) {
    unsigned r;
    asm("v_cvt_pk_bf16_f32 %0, %1, %2" : "=v"(r) : "v"(a), "v"(b));
    return r;
}

// Workgroup barrier that drains ONLY LDS ops (lgkmcnt), not global loads
// (vmcnt): global prefetches stay in flight across the barrier.
static __device__ __forceinline__ void barrier_lgkm() {
    asm volatile("s_waitcnt lgkmcnt(0)" ::: "memory");
    __builtin_amdgcn_s_barrier();
}

// De-phase co-resident blocks.
static __device__ __forceinline__ void stagger_block() {
    const unsigned flat = blockIdx.x + gridDim.x * (blockIdx.y + gridDim.y * blockIdx.z);
    const int slot = (int)(flat % 5u);
    #pragma unroll
    for (int i = 0; i < 4; ++i)
        if (i < slot) __builtin_amdgcn_s_sleep(6);
}

// ---------------------------------------------------------------------------
// Pre-pack kernels: fp32 -> [K/32 ktiles][rows][64 shorts = hi32|lo32] with
// the (row&7) XOR granule swizzle BAKED INTO MEMORY, so GEMM staging is a
// pure linear 16B copy and fragment reads use the standard XOR formulas.
// ---------------------------------------------------------------------------
__global__ __launch_bounds__(256) void pack_rows_hl(const float* __restrict__ src,
                                                    unsigned short* __restrict__ dst,
                                                    int Mtot, int K)
{
    const int m = blockIdx.x * 256 + threadIdx.x;
    const int t = blockIdx.y;
    const float* sp = src + (size_t)m * K + t * 32;
    unsigned short buf[64];
    #pragma unroll
    for (int i = 0; i < 32; i += 4) {
        const float4 v = *(const float4*)&sp[i];
        *(uint2*)&buf[i]      = pack_hi4(v);
        *(uint2*)&buf[32 + i] = pack_lo4(v);
    }
    unsigned short* dp = dst + ((size_t)t * Mtot + m) * 64;
    const int s7 = m & 7;
    #pragma unroll
    for (int G = 0; G < 8; ++G)
        *(bf16x8*)&dp[(G ^ s7) * 8] = *(bf16x8*)&buf[G * 8];
}

__global__ __launch_bounds__(256) void pack_cols_hl(const float* __restrict__ src,
                                                    unsigned short* __restrict__ dst,
                                                    int Ntot)
{
    const int n = blockIdx.x * 256 + threadIdx.x;
    const int t = blockIdx.y;
    float vals[32];
    #pragma unroll
    for (int i = 0; i < 32; ++i) vals[i] = src[(size_t)(t * 32 + i) * Ntot + n];
    unsigned short buf[64];
    #pragma unroll
    for (int i = 0; i < 32; i += 4) {
        const float4 v = make_float4(vals[i], vals[i + 1], vals[i + 2], vals[i + 3]);
        *(uint2*)&buf[i]      = pack_hi4(v);
        *(uint2*)&buf[32 + i] = pack_lo4(v);
    }
    unsigned short* dp = dst + ((size_t)t * Ntot + n) * 64;
    const int s7 = n & 7;
    #pragma unroll
    for (int G = 0; G < 8; ++G)
        *(bf16x8*)&dp[(G ^ s7) * 8] = *(bf16x8*)&buf[G * 8];
}

// ---------------------------------------------------------------------------
// Packed bf16x3 GEMM core, 256x128 block tile, 512 threads = 8 waves
// (4M x 2N; per-wave 64x64 = the verified acc[4][4] fragment map).
// Per K-step MFMA (~1860cy) dominates LDS (~690cy) -> staging hides under
// the MFMA phase. Depth-2 write-after-read schedule, lgkmcnt-only barrier.
// ---------------------------------------------------------------------------
static __device__ __forceinline__ void gemm_core_pk8(const unsigned short* __restrict__ Ap,
                                                     const unsigned short* __restrict__ Bp,
                                                     unsigned short* As,   // [2*256*64]
                                                     unsigned short* Bs,   // [2*128*64]
                                                     f32x4 (&acc)[4][4],
                                                     int Mtot, int Ntot, int NT,
                                                     int row0, int col0)
{
    const int tid  = threadIdx.x;
    const int lane = tid & 63;
    const int w    = tid >> 6;        // 0..7
    const int l15  = lane & 15;
    const int g    = lane >> 4;
    const int wr   = w >> 1;          // 0..3 (M)
    const int wc   = w & 1;           // 0..1 (N)

    const unsigned short* aSrc = Ap + (size_t)row0 * 64 + tid * 8;
    const unsigned short* bSrc = Bp + (size_t)col0 * 64 + tid * 8;
    const size_t aStep = (size_t)Mtot * 64;
    const size_t bStep = (size_t)Ntot * 64;

    int aoff[4][2], boff[4][2];
    #pragma unroll
    for (int mt = 0; mt < 4; ++mt) {
        const int m = wr * 64 + mt * 16 + l15;          // 0..255
        const int sw = (m & 7) << 3;
        aoff[mt][0] = m * 64 + ((g * 8) ^ sw);
        aoff[mt][1] = m * 64 + ((32 + g * 8) ^ sw);
    }
    #pragma unroll
    for (int nt = 0; nt < 4; ++nt) {
        const int n = wc * 64 + nt * 16 + l15;          // 0..127
        const int sw = (n & 7) << 3;
        boff[nt][0] = n * 64 + ((g * 8) ^ sw);
        boff[nt][1] = n * 64 + ((32 + g * 8) ^ sw);
    }

    bf16x8 ar[4], br[2];
    #pragma unroll
    for (int p = 0; p < 4; ++p) ar[p] = *(const bf16x8*)(aSrc + p * 4096);
    #pragma unroll
    for (int p = 0; p < 2; ++p) br[p] = *(const bf16x8*)(bSrc + p * 4096);
    #pragma unroll
    for (int p = 0; p < 4; ++p) *(bf16x8*)&As[tid * 8 + p * 4096] = ar[p];
    #pragma unroll
    for (int p = 0; p < 2; ++p) *(bf16x8*)&Bs[tid * 8 + p * 4096] = br[p];
    if (1 < NT) {
        #pragma unroll
        for (int p = 0; p < 4; ++p) ar[p] = *(const bf16x8*)(aSrc + aStep + p * 4096);
        #pragma unroll
        for (int p = 0; p < 2; ++p) br[p] = *(const bf16x8*)(bSrc + bStep + p * 4096);
    }
    __syncthreads();

    int cur = 0;
    for (int t = 0; t < NT; ++t) {
        const int ca = cur * 16384, cb = cur * 8192;
        bf16x8 ah[4], al[4], bh[4], bl[4];
        #pragma unroll
        for (int mt = 0; mt < 4; ++mt) {
            ah[mt] = *(const bf16x8*)&As[ca + aoff[mt][0]];
            al[mt] = *(const bf16x8*)&As[ca + aoff[mt][1]];
        }
        #pragma unroll
        for (int nt = 0; nt < 4; ++nt) {
            bh[nt] = *(const bf16x8*)&Bs[cb + boff[nt][0]];
            bl[nt] = *(const bf16x8*)&Bs[cb + boff[nt][1]];
        }
        if (t + 1 < NT) {
            const int na = (cur ^ 1) * 16384, nb = (cur ^ 1) * 8192;
            #pragma unroll
            for (int p = 0; p < 4; ++p)
                *(bf16x8*)&As[na + tid * 8 + p * 4096] = ar[p];
            #pragma unroll
            for (int p = 0; p < 2; ++p)
                *(bf16x8*)&Bs[nb + tid * 8 + p * 4096] = br[p];
        }
        if (t + 2 < NT) {
            const unsigned short* a2 = aSrc + (size_t)(t + 2) * aStep;
            const unsigned short* b2 = bSrc + (size_t)(t + 2) * bStep;
            #pragma unroll
            for (int p = 0; p < 4; ++p) ar[p] = *(const bf16x8*)(a2 + p * 4096);
            #pragma unroll
            for (int p = 0; p < 2; ++p) br[p] = *(const bf16x8*)(b2 + p * 4096);
        }
        #pragma unroll
        for (int mt = 0; mt < 4; ++mt)
            #pragma unroll
            for (int nt = 0; nt < 4; ++nt) {
                acc[mt][nt] = MFMA16(ah[mt], bh[nt], acc[mt][nt]);
                acc[mt][nt] = MFMA16(ah[mt], bl[nt], acc[mt][nt]);
                acc[mt][nt] = MFMA16(al[mt], bh[nt], acc[mt][nt]);
            }
        barrier_lgkm();
        cur ^= 1;
    }
}

// ---------------------------------------------------------------------------
// Out-projection GEMM: packed A (from attn) x packed w_out -> fp32 + bias.
// ---------------------------------------------------------------------------
__global__ __launch_bounds__(512, 2) void gemm_out_pk(const unsigned short* __restrict__ Ap,
                                                      const unsigned short* __restrict__ Bp,
                                                      const float* __restrict__ bias,
                                                      float* __restrict__ C)
{
    __shared__ unsigned short As[2 * 256 * 64];
    __shared__ unsigned short Bs[2 * 128 * 64];

    const int tid  = threadIdx.x;
    const int lane = tid & 63;
    const int w    = tid >> 6;
    const int l15  = lane & 15;
    const int g    = lane >> 4;
    const int wr   = w >> 1, wc = w & 1;
    const int row0 = blockIdx.y * 256, col0 = blockIdx.x * 128;

    f32x4 acc[4][4] = {};
    gemm_core_pk8(Ap, Bp, As, Bs, acc, MTOT, INNER, 32, row0, col0);

    #pragma unroll
    for (int nt = 0; nt < 4; ++nt) {
        const int c = col0 + wc * 64 + nt * 16 + l15;
        const float bv = bias[c];
        #pragma unroll
        for (int mt = 0; mt < 4; ++mt)
            #pragma unroll
            for (int r = 0; r < 4; ++r) {
                const int rr = row0 + wr * 64 + mt * 16 + g * 4 + r;
                C[(size_t)rr * INNER + c] = acc[mt][nt][r] + bv;
            }
    }
}

// ---------------------------------------------------------------------------
// QKV GEMM: 8-wave core + attention-ready epilogue (q/k hi-lo planes,
// V transposed + pi-permuted RN bf16).
// ---------------------------------------------------------------------------
__global__ __launch_bounds__(512, 2) void gemm_qkv_pk(const unsigned short* __restrict__ Ap,
                                                      const unsigned short* __restrict__ Bp,
                                                      unsigned short* __restrict__ q_hl,
                                                      unsigned short* __restrict__ k_hl,
                                                      unsigned short* __restrict__ vt)
{
    __shared__ unsigned short As[2 * 256 * 64];
    __shared__ unsigned short Bs[2 * 128 * 64];

    const int tid  = threadIdx.x;
    const int lane = tid & 63;
    const int w    = tid >> 6;
    const int l15  = lane & 15;
    const int g    = lane >> 4;
    const int wr   = w >> 1, wc = w & 1;
    const int row0 = blockIdx.y * 256, col0 = blockIdx.x * 128;

    f32x4 acc[4][4] = {};
    gemm_core_pk8(Ap, Bp, As, Bs, acc, MTOT, QKV_N, 32, row0, col0);

    if (col0 < 2 * INNER) {
        unsigned short* plane = (col0 < INNER) ? q_hl : k_hl;
        const float sc = (col0 < INNER) ? QSCALE : 1.0f;
        #pragma unroll
        for (int nt = 0; nt < 4; ++nt) {
            const int c  = col0 + wc * 64 + nt * 16 + l15;
            const int cc = c & (INNER - 1);
            const int hd = (cc >> 6) * 128 + (cc & 63);
            #pragma unroll
            for (int mt = 0; mt < 4; ++mt)
                #pragma unroll
                for (int r = 0; r < 4; ++r) {
                    const int rr = row0 + wr * 64 + mt * 16 + g * 4 + r;
                    const float v = acc[mt][nt][r] * sc;
                    const unsigned u = fau(v);
                    const float res = v - __uint_as_float(u & 0xffff0000u);
                    unsigned short* dp = plane + (size_t)rr * 2048 + hd;
                    dp[0]  = (unsigned short)(u >> 16);
                    dp[64] = (unsigned short)(fau(res) >> 16);
                }
        }
    } else {
        #pragma unroll
        for (int nt = 0; nt < 4; ++nt) {
            const int f = col0 + wc * 64 + nt * 16 + l15 - 2 * INNER;  // h*64+d
            #pragma unroll
            for (int mt = 0; mt < 4; ++mt) {
                const int rr0 = row0 + wr * 64 + mt * 16 + g * 4;      // token, %4==0
                const int bb  = rr0 >> 11;
                const int n   = rr0 & (SEQ - 1);
                const int pn  = (n & ~31) | ((n & 12) << 1) | ((n & 16) >> 2);
                const uint2 pk = make_uint2(
                    cvt_pk_bf16(acc[mt][nt][0], acc[mt][nt][1]),
                    cvt_pk_bf16(acc[mt][nt][2], acc[mt][nt][3]));
                *(uint2*)&vt[((size_t)bb * INNER + f) * SEQ + pn] = pk;
            }
        }
    }
}

// ---------------------------------------------------------------------------
// MFMA flash attention, 4 q-sets/wave, CROSS-ITERATION PV PIPELINE:
// per kv-iter: QK^T(kv) [96 MFMA] -> PV(kv-1) [32 MFMA] -> softmax(kv)
// [VALU]. The softmax does not depend on PV (rescale is after PV and rare),
// so its VALU executes under the queued PV MFMAs instead of serializing
// between the two MFMA blocks. Accumulation order rescale(kv-1) -> PV(kv-1)
// -> rescale(kv) -> PV(kv) is bit-identical to the unpipelined kernel.
// V is 4-buffered (lifetime 2 + barrier-distance safety); K stays 2-buffered.
// ---------------------------------------------------------------------------
__global__ __launch_bounds__(256, 2) void attn_mfma(const unsigned short* __restrict__ q_hl,
                                                    const unsigned short* __restrict__ k_hl,
                                                    const unsigned short* __restrict__ vt,
                                                    unsigned short* __restrict__ ao_hl)
{
    __shared__ unsigned short Ks[2 * 64 * 128];  // 2-buffered, XOR-swizzled
    __shared__ unsigned short Vs[4 * 64 * 64];   // 4-buffered (PV uses kv-1)

    stagger_block();

    const int tid  = threadIdx.x;
    const int lane = tid & 63;
    const int w    = tid >> 6;
    const int l15  = lane & 15;
    const int g    = lane >> 4;
    const int h  = blockIdx.x, qb = blockIdx.y, b = blockIdx.z;
    const int q0 = qb * 256 + w * 64;

    // Q fragments (B-operand layout: lane holds Q[q][kk*32+8g..+8], hi+lo).
    bf16x8 qh[4][2], ql[4][2];
    #pragma unroll
    for (int qs = 0; qs < 4; ++qs) {
        const unsigned short* qp =
            q_hl + (size_t)(b * SEQ + q0 + qs * 16 + l15) * 2048 + h * 128;
        #pragma unroll
        for (int kk = 0; kk < 2; ++kk) {
            qh[qs][kk] = *(const bf16x8*)&qp[kk * 32 + g * 8];
            ql[qs][kk] = *(const bf16x8*)&qp[64 + kk * 32 + g * 8];
        }
    }

    f32x4 o[4][4] = {};                    // [qs][nt]: O[q=4g+r][d=nt*16+l15]
    float m_run[4] = {-1e30f, -1e30f, -1e30f, -1e30f};
    float l_run[4] = {0.f, 0.f, 0.f, 0.f};
    bf16x8 pav[4][2];                      // P(kv) fragments, consumed at kv+1

    // Staging address precompute (pure copies; all swizzle math hoisted).
    const int kj   = tid >> 4;                         // K row within 16-row pass
    const int ko8  = (tid & 15) * 8;
    const int kdst = kj * 128 + (ko8 ^ (kj << 3));
    const unsigned short* ksrc =
        k_hl + ((size_t)(b * SEQ + kj)) * 2048 + h * 128 + ko8;

    const int vd   = tid >> 3;                         // V row within 32-row pass
    const int vu8  = (tid & 7) * 8;
    const int vdst = vd * 64 + (vu8 ^ ((vd & 7) << 3));
    const unsigned short* vsrc =
        vt + ((size_t)(b * HEADS + h) * 64 + vd) * SEQ + vu8;

    // Fragment read offsets.
    const int krow = l15 * 128;
    int koff[2][2];
    #pragma unroll
    for (int kk = 0; kk < 2; ++kk) {
        koff[kk][0] = (kk * 32 + g * 8) ^ (l15 * 8);
        koff[kk][1] = (64 + kk * 32 + g * 8) ^ (l15 * 8);
    }
    const int vrow = l15 * 64;
    const int voff[2] = { (g * 8) ^ ((l15 & 7) * 8), (32 + g * 8) ^ ((l15 & 7) * 8) };

    // Prologue: prefetch tile 0 into regs.
    bf16x8 kr[4], vr[2];
    #pragma unroll
    for (int p = 0; p < 4; ++p)
        kr[p] = *(const bf16x8*)&ksrc[(size_t)(p * 16) * 2048];
    #pragma unroll
    for (int p = 0; p < 2; ++p)
        vr[p] = *(const bf16x8*)&vsrc[(size_t)p * 32 * SEQ];

    for (int kv = 0; kv < SEQ / 64; ++kv) {
        // Stage tile kv: K into 2-buf (kv&1), V into 4-buf (kv&3).
        const int kb  = (kv & 1) * 8192;
        const int vbw = (kv & 3) * 4096;
        #pragma unroll
        for (int p = 0; p < 4; ++p)
            *(bf16x8*)&Ks[kb + p * 2048 + kdst] = kr[p];
        #pragma unroll
        for (int p = 0; p < 2; ++p)
            *(bf16x8*)&Vs[vbw + p * 2048 + vdst] = vr[p];
        barrier_lgkm();
        if (kv + 1 < SEQ / 64) {
            const int j0n = (kv + 1) * 64;
            #pragma unroll
            for (int p = 0; p < 4; ++p)
                kr[p] = *(const bf16x8*)&ksrc[(size_t)(j0n + p * 16) * 2048];
            #pragma unroll
            for (int p = 0; p < 2; ++p)
                vr[p] = *(const bf16x8*)&vsrc[(size_t)p * 32 * SEQ + j0n];
        }

        // QK^T(kv) (swapped, bf16x3): each K fragment read feeds all 4 q-sets.
        f32x4 s[4][4] = {};
        __builtin_amdgcn_s_setprio(1);
        #pragma unroll
        for (int jt = 0; jt < 4; ++jt) {
            #pragma unroll
            for (int kk = 0; kk < 2; ++kk) {
                const bf16x8 khf = *(const bf16x8*)&Ks[kb + jt * 2048 + krow + koff[kk][0]];
                const bf16x8 klf = *(const bf16x8*)&Ks[kb + jt * 2048 + krow + koff[kk][1]];
                #pragma unroll
                for (int qs = 0; qs < 4; ++qs) {
                    s[qs][jt] = MFMA16(khf, qh[qs][kk], s[qs][jt]);
                    s[qs][jt] = MFMA16(khf, ql[qs][kk], s[qs][jt]);
                    s[qs][jt] = MFMA16(klf, qh[qs][kk], s[qs][jt]);
                }
            }
        }

        // PV(kv-1): o += P(kv-1) * V(kv-1). Queued behind QK^T on the matrix
        // pipe; the softmax VALU below executes under it.
        if (kv) {
            const int vbr = ((kv + 3) & 3) * 4096;
            #pragma unroll
            for (int t = 0; t < 2; ++t)
                #pragma unroll
                for (int nt = 0; nt < 4; ++nt) {
                    const bf16x8 vbv = *(const bf16x8*)&Vs[vbr + nt * 1024 + vrow + voff[t]];
                    #pragma unroll
                    for (int qs = 0; qs < 4; ++qs)
                        o[qs][nt] = MFMA16(pav[qs][t], vbv, o[qs][nt]);
                }
        }
        __builtin_amdgcn_s_setprio(0);

        // Softmax(kv) (log2 domain, defer-max) + packed P -> pav, per q-set.
        // Rescale (rare) comes after PV(kv-1) in program order -> exact
        // online-softmax ordering preserved.
        #pragma unroll
        for (int qs = 0; qs < 4; ++qs) {
            const f32x4* sq = s[qs];
            float mx = max3f(sq[0][0], sq[0][1], sq[0][2]);
            mx = max3f(mx, sq[0][3], sq[1][0]);
            mx = max3f(mx, sq[1][1], sq[1][2]);
            mx = max3f(mx, sq[1][3], sq[2][0]);
            mx = max3f(mx, sq[2][1], sq[2][2]);
            mx = max3f(mx, sq[2][3], sq[3][0]);
            mx = max3f(mx, sq[3][1], sq[3][2]);
            mx = fmaxf(mx, sq[3][3]);
            mx = fmaxf(mx, __shfl_xor(mx, 16));
            mx = fmaxf(mx, __shfl_xor(mx, 32));
            if (!__all(mx - m_run[qs] <= 8.f)) {
                const float mnew = fmaxf(m_run[qs], mx);
                const float corr = __builtin_amdgcn_exp2f(m_run[qs] - mnew);
                m_run[qs] = mnew;
                l_run[qs] *= corr;
                const float cr0 = __shfl(corr, g * 4 + 0);
                const float cr1 = __shfl(corr, g * 4 + 1);
                const float cr2 = __shfl(corr, g * 4 + 2);
                const float cr3 = __shfl(corr, g * 4 + 3);
                #pragma unroll
                for (int nt = 0; nt < 4; ++nt) {
                    o[qs][nt][0] *= cr0; o[qs][nt][1] *= cr1;
                    o[qs][nt][2] *= cr2; o[qs][nt][3] *= cr3;
                }
            }
            float sm = 0.f;
            #pragma unroll
            for (int jt = 0; jt < 4; ++jt)
                #pragma unroll
                for (int r = 0; r < 4; ++r) {
                    const float e = __builtin_amdgcn_exp2f(s[qs][jt][r] - m_run[qs]);
                    s[qs][jt][r] = e; sm += e;
                }
            sm += __shfl_xor(sm, 16);
            sm += __shfl_xor(sm, 32);
            l_run[qs] += sm;

            #pragma unroll
            for (int t = 0; t < 2; ++t) {
                union { uint2 u[2]; bf16x8 v; } P;
                P.u[0] = make_uint2(cvt_pk_bf16(s[qs][2 * t][0],     s[qs][2 * t][1]),
                                    cvt_pk_bf16(s[qs][2 * t][2],     s[qs][2 * t][3]));
                P.u[1] = make_uint2(cvt_pk_bf16(s[qs][2 * t + 1][0], s[qs][2 * t + 1][1]),
                                    cvt_pk_bf16(s[qs][2 * t + 1][2], s[qs][2 * t + 1][3]));
                pav[qs][t] = P.v;
            }
        }
    }

    // Drain the pipeline: PV for the final tile (kv = SEQ/64 - 1).
    {
        const int vbr = ((SEQ / 64 - 1) & 3) * 4096;
        __builtin_amdgcn_s_setprio(1);
        #pragma unroll
        for (int t = 0; t < 2; ++t)
            #pragma unroll
            for (int nt = 0; nt < 4; ++nt) {
                const bf16x8 vbv = *(const bf16x8*)&Vs[vbr + nt * 1024 + vrow + voff[t]];
                #pragma unroll
                for (int qs = 0; qs < 4; ++qs)
                    o[qs][nt] = MFMA16(pav[qs][t], vbv, o[qs][nt]);
            }
        __builtin_amdgcn_s_setprio(0);
    }

    // Epilogue: normalize by 1/l per O-row and store PACKED hi/lo into
    // ao_hl[ktile][M][64] with the (M&7) granule swizzle baked in.
    #pragma unroll
    for (int qs = 0; qs < 4; ++qs) {
        const float il = 1.f / l_run[qs];
        const float nr0 = __shfl(il, g * 4 + 0);
        const float nr1 = __shfl(il, g * 4 + 1);
        const float nr2 = __shfl(il, g * 4 + 2);
        const float nr3 = __shfl(il, g * 4 + 3);
        const float nr[4] = {nr0, nr1, nr2, nr3};
        #pragma unroll
        for (int nt = 0; nt < 4; ++nt) {
            const int k  = h * DHEAD + nt * 16 + l15;
            const int t  = k >> 5;
            const int kk = k & 31;
            const int G  = kk >> 3;   // 0..3
            const int e  = kk & 7;
            #pragma unroll
            for (int r = 0; r < 4; ++r) {
                const int M  = b * SEQ + q0 + qs * 16 + g * 4 + r;
                const int s7 = M & 7;
                unsigned short* dp = ao_hl + ((size_t)t * MTOT + M) * 64;
                const float v = o[qs][nt][r] * nr[r];
                const unsigned u = fau(v);
                const float res = v - __uint_as_float(u & 0xffff0000u);
                dp[((G ^ s7) << 3) + e]       = (unsigned short)(u >> 16);
                dp[(((G + 4) ^ s7) << 3) + e] = (unsigned short)(fau(res) >> 16);
            }
        }
    }
}

// ---------------------------------------------------------------------------
extern "C" void kernel_launch(void* const* d_in, const int* in_sizes, int n_in,
                              void* d_out, int out_size, void* d_ws, size_t ws_size,
                              hipStream_t stream)
{
    const float* x     = (const float*)d_in[0];  // [4,2048,1024]
    const float* w_qkv = (const float*)d_in[1];  // [1024,3072]
    const float* w_out = (const float*)d_in[2];  // [1024,1024]
    const float* b_out = (const float*)d_in[3];  // [1024]
    float* out = (float*)d_out;                  // [4,2048,1024]

    // Workspace (exactly 128 MiB):
    //   q_hl 32M | k_hl 32M | vt 16M | xa_hl 32M (x pack, reused as ao pack)
    //   | wq_hl 12M | wo_hl 4M
    unsigned short* q_hl  = (unsigned short*)d_ws;
    unsigned short* k_hl  = q_hl  + (size_t)MTOT * 2048;
    unsigned short* vt    = k_hl  + (size_t)MTOT * 2048;
    unsigned short* xa_hl = vt    + (size_t)BATCH * INNER * SEQ;
    unsigned short* wq_hl = xa_hl + (size_t)32 * MTOT * 64;
    unsigned short* wo_hl = wq_hl + (size_t)32 * QKV_N * 64;

    pack_rows_hl<<<dim3(MTOT / 256, 32), 256, 0, stream>>>(x, xa_hl, MTOT, DIM);
    pack_cols_hl<<<dim3(QKV_N / 256, 32), 256, 0, stream>>>(w_qkv, wq_hl, QKV_N);
    pack_cols_hl<<<dim3(INNER / 256, 32), 256, 0, stream>>>(w_out, wo_hl, INNER);

    // 256x128 tile, 512 threads: grid (24, 32) = 768 blocks = exactly 3/CU.
    gemm_qkv_pk<<<dim3(QKV_N / 128, MTOT / 256), 512, 0, stream>>>(
        xa_hl, wq_hl, q_hl, k_hl, vt);

    // attn overwrites xa_hl (x pack no longer needed) with the packed output.
    // Grid order (h, qb, b): flat%8 = h%8 -> same-(b,h) q-blocks share an XCD.
    attn_mfma<<<dim3(HEADS, SEQ / 256, BATCH), 256, 0, stream>>>(
        q_hl, k_hl, vt, xa_hl);

    // 256 blocks = exactly 1/CU.
    gemm_out_pk<<<dim3(INNER / 128, MTOT / 256), 512, 0, stream>>>(
        xa_hl, wo_hl, b_out, out);
}

// Round 13
// 351.838 us; speedup vs baseline: 1.1768x; 1.1768x over previous
//
#include <hip/hip_runtime.h>
#include <hip/hip_bf16.h>

#define BATCH 4
#define SEQ   2048
#define DIM   1024
#define HEADS 16
#define DHEAD 64
#define INNER 1024   // HEADS*DHEAD
#define QKV_N 3072   // 3*INNER
#define MTOT  8192   // BATCH*SEQ

typedef short bf16x8 __attribute__((ext_vector_type(8)));
typedef float f32x4  __attribute__((ext_vector_type(4)));
#define MFMA16(a,b,c) __builtin_amdgcn_mfma_f32_16x16x32_bf16((a),(b),(c),0,0,0)

// log2(e) * dhead^-0.5  (scale folded into Q so softmax can use native exp2)
#define QSCALE 0.1803368801111204f

static __device__ __forceinline__ unsigned fau(float f) { return __float_as_uint(f); }
static __device__ __forceinline__ float max3f(float a, float b, float c) {
    return fmaxf(fmaxf(a, b), c);   // clang fuses to v_max3_f32
}

// Truncate-to-bf16 pack of 4 floats (hi plane). Packs 4 bf16 into uint2.
static __device__ __forceinline__ uint2 pack_hi4(float4 v) {
    return make_uint2((fau(v.x) >> 16) | (fau(v.y) & 0xffff0000u),
                      (fau(v.z) >> 16) | (fau(v.w) & 0xffff0000u));
}
static __device__ __forceinline__ float4 resid4(float4 v) {
    float4 r;
    r.x = v.x - __uint_as_float(fau(v.x) & 0xffff0000u);
    r.y = v.y - __uint_as_float(fau(v.y) & 0xffff0000u);
    r.z = v.z - __uint_as_float(fau(v.z) & 0xffff0000u);
    r.w = v.w - __uint_as_float(fau(v.w) & 0xffff0000u);
    return r;
}
static __device__ __forceinline__ uint2 pack_lo4(float4 v) { return pack_hi4(resid4(v)); }

// Packed RNE fp32->bf16 pair: dst[15:0]=bf16(a), dst[31:16]=bf16(b).
static __device__ __forceinline__ unsigned cvt_pk_bf16(float a, float b) {
    unsigned r;
    asm("v_cvt_pk_bf16_f32 %0, %1, %2" : "=v"(r) : "v"(a), "v"(b));
    return r;
}

// Workgroup barrier that drains ONLY LDS ops (lgkmcnt), not global loads
// (vmcnt): global prefetches stay in flight across the barrier.
static __device__ __forceinline__ void barrier_lgkm() {
    asm volatile("s_waitcnt lgkmcnt(0)" ::: "memory");
    __builtin_amdgcn_s_barrier();
}

// De-phase co-resident blocks.
static __device__ __forceinline__ void stagger_block() {
    const unsigned flat = blockIdx.x + gridDim.x * (blockIdx.y + gridDim.y * blockIdx.z);
    const int slot = (int)(flat % 5u);
    #pragma unroll
    for (int i = 0; i < 4; ++i)
        if (i < slot) __builtin_amdgcn_s_sleep(6);
}

// ---------------------------------------------------------------------------
// Pre-pack kernels: fp32 -> [K/32 ktiles][rows][64 shorts = hi32|lo32] with
// the (row&7) XOR granule swizzle BAKED INTO MEMORY, so GEMM staging is a
// pure linear 16B copy and fragment reads use the standard XOR formulas.
// ---------------------------------------------------------------------------
__global__ __launch_bounds__(256) void pack_rows_hl(const float* __restrict__ src,
                                                    unsigned short* __restrict__ dst,
                                                    int Mtot, int K)
{
    const int m = blockIdx.x * 256 + threadIdx.x;
    const int t = blockIdx.y;
    const float* sp = src + (size_t)m * K + t * 32;
    unsigned short buf[64];
    #pragma unroll
    for (int i = 0; i < 32; i += 4) {
        const float4 v = *(const float4*)&sp[i];
        *(uint2*)&buf[i]      = pack_hi4(v);
        *(uint2*)&buf[32 + i] = pack_lo4(v);
    }
    unsigned short* dp = dst + ((size_t)t * Mtot + m) * 64;
    const int s7 = m & 7;
    #pragma unroll
    for (int G = 0; G < 8; ++G)
        *(bf16x8*)&dp[(G ^ s7) * 8] = *(bf16x8*)&buf[G * 8];
}

__global__ __launch_bounds__(256) void pack_cols_hl(const float* __restrict__ src,
                                                    unsigned short* __restrict__ dst,
                                                    int Ntot)
{
    const int n = blockIdx.x * 256 + threadIdx.x;
    const int t = blockIdx.y;
    float vals[32];
    #pragma unroll
    for (int i = 0; i < 32; ++i) vals[i] = src[(size_t)(t * 32 + i) * Ntot + n];
    unsigned short buf[64];
    #pragma unroll
    for (int i = 0; i < 32; i += 4) {
        const float4 v = make_float4(vals[i], vals[i + 1], vals[i + 2], vals[i + 3]);
        *(uint2*)&buf[i]      = pack_hi4(v);
        *(uint2*)&buf[32 + i] = pack_lo4(v);
    }
    unsigned short* dp = dst + ((size_t)t * Ntot + n) * 64;
    const int s7 = n & 7;
    #pragma unroll
    for (int G = 0; G < 8; ++G)
        *(bf16x8*)&dp[(G ^ s7) * 8] = *(bf16x8*)&buf[G * 8];
}

// ---------------------------------------------------------------------------
// Packed bf16x3 GEMM core, 256x128 block tile, 512 threads = 8 waves
// (4M x 2N; per-wave 64x64 = the verified acc[4][4] fragment map).
// Per K-step MFMA (~1860cy) dominates LDS (~690cy) -> staging hides under
// the MFMA phase. Depth-2 write-after-read schedule, lgkmcnt-only barrier.
// (Round-11 verbatim — the session's verified best GEMM.)
// ---------------------------------------------------------------------------
static __device__ __forceinline__ void gemm_core_pk8(const unsigned short* __restrict__ Ap,
                                                     const unsigned short* __restrict__ Bp,
                                                     unsigned short* As,   // [2*256*64]
                                                     unsigned short* Bs,   // [2*128*64]
                                                     f32x4 (&acc)[4][4],
                                                     int Mtot, int Ntot, int NT,
                                                     int row0, int col0)
{
    const int tid  = threadIdx.x;
    const int lane = tid & 63;
    const int w    = tid >> 6;        // 0..7
    const int l15  = lane & 15;
    const int g    = lane >> 4;
    const int wr   = w >> 1;          // 0..3 (M)
    const int wc   = w & 1;           // 0..1 (N)

    const unsigned short* aSrc = Ap + (size_t)row0 * 64 + tid * 8;
    const unsigned short* bSrc = Bp + (size_t)col0 * 64 + tid * 8;
    const size_t aStep = (size_t)Mtot * 64;
    const size_t bStep = (size_t)Ntot * 64;

    int aoff[4][2], boff[4][2];
    #pragma unroll
    for (int mt = 0; mt < 4; ++mt) {
        const int m = wr * 64 + mt * 16 + l15;          // 0..255
        const int sw = (m & 7) << 3;
        aoff[mt][0] = m * 64 + ((g * 8) ^ sw);
        aoff[mt][1] = m * 64 + ((32 + g * 8) ^ sw);
    }
    #pragma unroll
    for (int nt = 0; nt < 4; ++nt) {
        const int n = wc * 64 + nt * 16 + l15;          // 0..127
        const int sw = (n & 7) << 3;
        boff[nt][0] = n * 64 + ((g * 8) ^ sw);
        boff[nt][1] = n * 64 + ((32 + g * 8) ^ sw);
    }

    bf16x8 ar[4], br[2];
    #pragma unroll
    for (int p = 0; p < 4; ++p) ar[p] = *(const bf16x8*)(aSrc + p * 4096);
    #pragma unroll
    for (int p = 0; p < 2; ++p) br[p] = *(const bf16x8*)(bSrc + p * 4096);
    #pragma unroll
    for (int p = 0; p < 4; ++p) *(bf16x8*)&As[tid * 8 + p * 4096] = ar[p];
    #pragma unroll
    for (int p = 0; p < 2; ++p) *(bf16x8*)&Bs[tid * 8 + p * 4096] = br[p];
    if (1 < NT) {
        #pragma unroll
        for (int p = 0; p < 4; ++p) ar[p] = *(const bf16x8*)(aSrc + aStep + p * 4096);
        #pragma unroll
        for (int p = 0; p < 2; ++p) br[p] = *(const bf16x8*)(bSrc + bStep + p * 4096);
    }
    __syncthreads();

    int cur = 0;
    for (int t = 0; t < NT; ++t) {
        const int ca = cur * 16384, cb = cur * 8192;
        bf16x8 ah[4], al[4], bh[4], bl[4];
        #pragma unroll
        for (int mt = 0; mt < 4; ++mt) {
            ah[mt] = *(const bf16x8*)&As[ca + aoff[mt][0]];
            al[mt] = *(const bf16x8*)&As[ca + aoff[mt][1]];
        }
        #pragma unroll
        for (int nt = 0; nt < 4; ++nt) {
            bh[nt] = *(const bf16x8*)&Bs[cb + boff[nt][0]];
            bl[nt] = *(const bf16x8*)&Bs[cb + boff[nt][1]];
        }
        if (t + 1 < NT) {
            const int na = (cur ^ 1) * 16384, nb = (cur ^ 1) * 8192;
            #pragma unroll
            for (int p = 0; p < 4; ++p)
                *(bf16x8*)&As[na + tid * 8 + p * 4096] = ar[p];
            #pragma unroll
            for (int p = 0; p < 2; ++p)
                *(bf16x8*)&Bs[nb + tid * 8 + p * 4096] = br[p];
        }
        if (t + 2 < NT) {
            const unsigned short* a2 = aSrc + (size_t)(t + 2) * aStep;
            const unsigned short* b2 = bSrc + (size_t)(t + 2) * bStep;
            #pragma unroll
            for (int p = 0; p < 4; ++p) ar[p] = *(const bf16x8*)(a2 + p * 4096);
            #pragma unroll
            for (int p = 0; p < 2; ++p) br[p] = *(const bf16x8*)(b2 + p * 4096);
        }
        #pragma unroll
        for (int mt = 0; mt < 4; ++mt)
            #pragma unroll
            for (int nt = 0; nt < 4; ++nt) {
                acc[mt][nt] = MFMA16(ah[mt], bh[nt], acc[mt][nt]);
                acc[mt][nt] = MFMA16(ah[mt], bl[nt], acc[mt][nt]);
                acc[mt][nt] = MFMA16(al[mt], bh[nt], acc[mt][nt]);
            }
        barrier_lgkm();
        cur ^= 1;
    }
}

// ---------------------------------------------------------------------------
// Out-projection GEMM: packed A (from attn) x packed w_out -> fp32 + bias.
// ---------------------------------------------------------------------------
__global__ __launch_bounds__(512, 2) void gemm_out_pk(const unsigned short* __restrict__ Ap,
                                                      const unsigned short* __restrict__ Bp,
                                                      const float* __restrict__ bias,
                                                      float* __restrict__ C)
{
    __shared__ unsigned short As[2 * 256 * 64];
    __shared__ unsigned short Bs[2 * 128 * 64];

    const int tid  = threadIdx.x;
    const int lane = tid & 63;
    const int w    = tid >> 6;
    const int l15  = lane & 15;
    const int g    = lane >> 4;
    const int wr   = w >> 1, wc = w & 1;
    const int row0 = blockIdx.y * 256, col0 = blockIdx.x * 128;

    f32x4 acc[4][4] = {};
    gemm_core_pk8(Ap, Bp, As, Bs, acc, MTOT, INNER, 32, row0, col0);

    #pragma unroll
    for (int nt = 0; nt < 4; ++nt) {
        const int c = col0 + wc * 64 + nt * 16 + l15;
        const float bv = bias[c];
        #pragma unroll
        for (int mt = 0; mt < 4; ++mt)
            #pragma unroll
            for (int r = 0; r < 4; ++r) {
                const int rr = row0 + wr * 64 + mt * 16 + g * 4 + r;
                C[(size_t)rr * INNER + c] = acc[mt][nt][r] + bv;
            }
    }
}

// ---------------------------------------------------------------------------
// QKV GEMM: 8-wave core + attention-ready epilogue (q/k hi-lo planes,
// V transposed + pi-permuted RN bf16).
// ---------------------------------------------------------------------------
__global__ __launch_bounds__(512, 2) void gemm_qkv_pk(const unsigned short* __restrict__ Ap,
                                                      const unsigned short* __restrict__ Bp,
                                                      unsigned short* __restrict__ q_hl,
                                                      unsigned short* __restrict__ k_hl,
                                                      unsigned short* __restrict__ vt)
{
    __shared__ unsigned short As[2 * 256 * 64];
    __shared__ unsigned short Bs[2 * 128 * 64];

    const int tid  = threadIdx.x;
    const int lane = tid & 63;
    const int w    = tid >> 6;
    const int l15  = lane & 15;
    const int g    = lane >> 4;
    const int wr   = w >> 1, wc = w & 1;
    const int row0 = blockIdx.y * 256, col0 = blockIdx.x * 128;

    f32x4 acc[4][4] = {};
    gemm_core_pk8(Ap, Bp, As, Bs, acc, MTOT, QKV_N, 32, row0, col0);

    if (col0 < 2 * INNER) {
        unsigned short* plane = (col0 < INNER) ? q_hl : k_hl;
        const float sc = (col0 < INNER) ? QSCALE : 1.0f;
        #pragma unroll
        for (int nt = 0; nt < 4; ++nt) {
            const int c  = col0 + wc * 64 + nt * 16 + l15;
            const int cc = c & (INNER - 1);
            const int hd = (cc >> 6) * 128 + (cc & 63);
            #pragma unroll
            for (int mt = 0; mt < 4; ++mt)
                #pragma unroll
                for (int r = 0; r < 4; ++r) {
                    const int rr = row0 + wr * 64 + mt * 16 + g * 4 + r;
                    const float v = acc[mt][nt][r] * sc;
                    const unsigned u = fau(v);
                    const float res = v - __uint_as_float(u & 0xffff0000u);
                    unsigned short* dp = plane + (size_t)rr * 2048 + hd;
                    dp[0]  = (unsigned short)(u >> 16);
                    dp[64] = (unsigned short)(fau(res) >> 16);
                }
        }
    } else {
        #pragma unroll
        for (int nt = 0; nt < 4; ++nt) {
            const int f = col0 + wc * 64 + nt * 16 + l15 - 2 * INNER;  // h*64+d
            #pragma unroll
            for (int mt = 0; mt < 4; ++mt) {
                const int rr0 = row0 + wr * 64 + mt * 16 + g * 4;      // token, %4==0
                const int bb  = rr0 >> 11;
                const int n   = rr0 & (SEQ - 1);
                const int pn  = (n & ~31) | ((n & 12) << 1) | ((n & 16) >> 2);
                const uint2 pk = make_uint2(
                    cvt_pk_bf16(acc[mt][nt][0], acc[mt][nt][1]),
                    cvt_pk_bf16(acc[mt][nt][2], acc[mt][nt][3]));
                *(uint2*)&vt[((size_t)bb * INNER + f) * SEQ + pn] = pk;
            }
        }
    }
}

// ---------------------------------------------------------------------------
// MFMA flash attention, 4 q-sets/wave. Round-11 structure (2-buf K/V,
// lgkmcnt barrier, stagger, setprio) with ONE change: softmax and PV are
// interleaved in qs-PAIRS — softmax(0,1) -> PV(0,1) -> softmax(2,3) ->
// PV(2,3). Pair-1 softmax (pure VALU, independent of pair-0 accumulators)
// executes under pair-0's 16 PV MFMAs. Per-qs op order (rescale -> exp ->
// pack -> PV) is unchanged -> bit-identical numerics. Cost: V fragments
// read twice per iter (+8 ds_read_b128, ~3% LDS traffic).
// ---------------------------------------------------------------------------
__global__ __launch_bounds__(256, 2) void attn_mfma(const unsigned short* __restrict__ q_hl,
                                                    const unsigned short* __restrict__ k_hl,
                                                    const unsigned short* __restrict__ vt,
                                                    unsigned short* __restrict__ ao_hl)
{
    __shared__ unsigned short Ks[2 * 64 * 128];  // double-buffered, XOR-swizzled
    __shared__ unsigned short Vs[2 * 64 * 64];

    stagger_block();

    const int tid  = threadIdx.x;
    const int lane = tid & 63;
    const int w    = tid >> 6;
    const int l15  = lane & 15;
    const int g    = lane >> 4;
    const int h  = blockIdx.x, qb = blockIdx.y, b = blockIdx.z;
    const int q0 = qb * 256 + w * 64;

    // Q fragments (B-operand layout: lane holds Q[q][kk*32+8g..+8], hi+lo).
    bf16x8 qh[4][2], ql[4][2];
    #pragma unroll
    for (int qs = 0; qs < 4; ++qs) {
        const unsigned short* qp =
            q_hl + (size_t)(b * SEQ + q0 + qs * 16 + l15) * 2048 + h * 128;
        #pragma unroll
        for (int kk = 0; kk < 2; ++kk) {
            qh[qs][kk] = *(const bf16x8*)&qp[kk * 32 + g * 8];
            ql[qs][kk] = *(const bf16x8*)&qp[64 + kk * 32 + g * 8];
        }
    }

    f32x4 o[4][4] = {};                    // [qs][nt]: O[q=4g+r][d=nt*16+l15]
    float m_run[4] = {-1e30f, -1e30f, -1e30f, -1e30f};
    float l_run[4] = {0.f, 0.f, 0.f, 0.f};

    // Staging address precompute (pure copies; all swizzle math hoisted).
    const int kj   = tid >> 4;                         // K row within 16-row pass
    const int ko8  = (tid & 15) * 8;
    const int kdst = kj * 128 + (ko8 ^ (kj << 3));
    const unsigned short* ksrc =
        k_hl + ((size_t)(b * SEQ + kj)) * 2048 + h * 128 + ko8;

    const int vd   = tid >> 3;                         // V row within 32-row pass
    const int vu8  = (tid & 7) * 8;
    const int vdst = vd * 64 + (vu8 ^ ((vd & 7) << 3));
    const unsigned short* vsrc =
        vt + ((size_t)(b * HEADS + h) * 64 + vd) * SEQ + vu8;

    // Fragment read offsets.
    const int krow = l15 * 128;
    int koff[2][2];
    #pragma unroll
    for (int kk = 0; kk < 2; ++kk) {
        koff[kk][0] = (kk * 32 + g * 8) ^ (l15 * 8);
        koff[kk][1] = (64 + kk * 32 + g * 8) ^ (l15 * 8);
    }
    const int vrow = l15 * 64;
    const int voff[2] = { (g * 8) ^ ((l15 & 7) * 8), (32 + g * 8) ^ ((l15 & 7) * 8) };

    // Prologue: prefetch tile 0 into regs.
    bf16x8 kr[4], vr[2];
    #pragma unroll
    for (int p = 0; p < 4; ++p)
        kr[p] = *(const bf16x8*)&ksrc[(size_t)(p * 16) * 2048];
    #pragma unroll
    for (int p = 0; p < 2; ++p)
        vr[p] = *(const bf16x8*)&vsrc[(size_t)p * 32 * SEQ];

    int cur = 0;
    for (int kv = 0; kv < SEQ / 64; ++kv) {
        // Write prefetched tile into buf[cur]; lgkmcnt-only barrier orders
        // buffer reuse without draining the global prefetch queue.
        const int kb = cur * 8192, vb = cur * 4096;
        #pragma unroll
        for (int p = 0; p < 4; ++p)
            *(bf16x8*)&Ks[kb + p * 2048 + kdst] = kr[p];
        #pragma unroll
        for (int p = 0; p < 2; ++p)
            *(bf16x8*)&Vs[vb + p * 2048 + vdst] = vr[p];
        barrier_lgkm();
        if (kv + 1 < SEQ / 64) {
            const int j0n = (kv + 1) * 64;
            #pragma unroll
            for (int p = 0; p < 4; ++p)
                kr[p] = *(const bf16x8*)&ksrc[(size_t)(j0n + p * 16) * 2048];
            #pragma unroll
            for (int p = 0; p < 2; ++p)
                vr[p] = *(const bf16x8*)&vsrc[(size_t)p * 32 * SEQ + j0n];
        }

        // QK^T (swapped, bf16x3): each K fragment read feeds all 4 q-sets.
        f32x4 s[4][4] = {};
        __builtin_amdgcn_s_setprio(1);
        #pragma unroll
        for (int jt = 0; jt < 4; ++jt) {
            #pragma unroll
            for (int kk = 0; kk < 2; ++kk) {
                const bf16x8 khf = *(const bf16x8*)&Ks[kb + jt * 2048 + krow + koff[kk][0]];
                const bf16x8 klf = *(const bf16x8*)&Ks[kb + jt * 2048 + krow + koff[kk][1]];
                #pragma unroll
                for (int qs = 0; qs < 4; ++qs) {
                    s[qs][jt] = MFMA16(khf, qh[qs][kk], s[qs][jt]);
                    s[qs][jt] = MFMA16(khf, ql[qs][kk], s[qs][jt]);
                    s[qs][jt] = MFMA16(klf, qh[qs][kk], s[qs][jt]);
                }
            }
        }
        __builtin_amdgcn_s_setprio(0);

        // Softmax + PV in qs-pairs: softmax(2qp..2qp+1) then PV of that pair;
        // the NEXT pair's softmax runs on the VALU under this pair's MFMAs.
        #pragma unroll
        for (int qp = 0; qp < 2; ++qp) {
            bf16x8 pav[2][2];
            #pragma unroll
            for (int qi = 0; qi < 2; ++qi) {
                const int qs = qp * 2 + qi;
                const f32x4* sq = s[qs];
                float mx = max3f(sq[0][0], sq[0][1], sq[0][2]);
                mx = max3f(mx, sq[0][3], sq[1][0]);
                mx = max3f(mx, sq[1][1], sq[1][2]);
                mx = max3f(mx, sq[1][3], sq[2][0]);
                mx = max3f(mx, sq[2][1], sq[2][2]);
                mx = max3f(mx, sq[2][3], sq[3][0]);
                mx = max3f(mx, sq[3][1], sq[3][2]);
                mx = fmaxf(mx, sq[3][3]);
                mx = fmaxf(mx, __shfl_xor(mx, 16));
                mx = fmaxf(mx, __shfl_xor(mx, 32));
                // Defer-max: rescale only if a q-row's max grew past m_run+8.
                if (!__all(mx - m_run[qs] <= 8.f)) {
                    const float mnew = fmaxf(m_run[qs], mx);
                    const float corr = __builtin_amdgcn_exp2f(m_run[qs] - mnew);
                    m_run[qs] = mnew;
                    l_run[qs] *= corr;
                    const float cr0 = __shfl(corr, g * 4 + 0);
                    const float cr1 = __shfl(corr, g * 4 + 1);
                    const float cr2 = __shfl(corr, g * 4 + 2);
                    const float cr3 = __shfl(corr, g * 4 + 3);
                    #pragma unroll
                    for (int nt = 0; nt < 4; ++nt) {
                        o[qs][nt][0] *= cr0; o[qs][nt][1] *= cr1;
                        o[qs][nt][2] *= cr2; o[qs][nt][3] *= cr3;
                    }
                }
                float sm = 0.f;
                #pragma unroll
                for (int jt = 0; jt < 4; ++jt)
                    #pragma unroll
                    for (int r = 0; r < 4; ++r) {
                        const float e = __builtin_amdgcn_exp2f(s[qs][jt][r] - m_run[qs]);
                        s[qs][jt][r] = e; sm += e;
                    }
                sm += __shfl_xor(sm, 16);
                sm += __shfl_xor(sm, 32);
                l_run[qs] += sm;

                #pragma unroll
                for (int t = 0; t < 2; ++t) {
                    union { uint2 u[2]; bf16x8 v; } P;
                    P.u[0] = make_uint2(cvt_pk_bf16(s[qs][2 * t][0],     s[qs][2 * t][1]),
                                        cvt_pk_bf16(s[qs][2 * t][2],     s[qs][2 * t][3]));
                    P.u[1] = make_uint2(cvt_pk_bf16(s[qs][2 * t + 1][0], s[qs][2 * t + 1][1]),
                                        cvt_pk_bf16(s[qs][2 * t + 1][2], s[qs][2 * t + 1][3]));
                    pav[qi][t] = P.v;
                }
            }
            // PV for this pair; next pair's softmax overlaps these MFMAs.
            __builtin_amdgcn_s_setprio(1);
            #pragma unroll
            for (int t = 0; t < 2; ++t)
                #pragma unroll
                for (int nt = 0; nt < 4; ++nt) {
                    const bf16x8 vbv = *(const bf16x8*)&Vs[vb + nt * 1024 + vrow + voff[t]];
                    o[qp * 2 + 0][nt] = MFMA16(pav[0][t], vbv, o[qp * 2 + 0][nt]);
                    o[qp * 2 + 1][nt] = MFMA16(pav[1][t], vbv, o[qp * 2 + 1][nt]);
                }
            __builtin_amdgcn_s_setprio(0);
        }
        cur ^= 1;
    }

    // Epilogue: normalize by 1/l per O-row and store PACKED hi/lo into
    // ao_hl[ktile][M][64] with the (M&7) granule swizzle baked in.
    #pragma unroll
    for (int qs = 0; qs < 4; ++qs) {
        const float il = 1.f / l_run[qs];
        const float nr0 = __shfl(il, g * 4 + 0);
        const float nr1 = __shfl(il, g * 4 + 1);
        const float nr2 = __shfl(il, g * 4 + 2);
        const float nr3 = __shfl(il, g * 4 + 3);
        const float nr[4] = {nr0, nr1, nr2, nr3};
        #pragma unroll
        for (int nt = 0; nt < 4; ++nt) {
            const int k  = h * DHEAD + nt * 16 + l15;
            const int t  = k >> 5;
            const int kk = k & 31;
            const int G  = kk >> 3;   // 0..3
            const int e  = kk & 7;
            #pragma unroll
            for (int r = 0; r < 4; ++r) {
                const int M  = b * SEQ + q0 + qs * 16 + g * 4 + r;
                const int s7 = M & 7;
                unsigned short* dp = ao_hl + ((size_t)t * MTOT + M) * 64;
                const float v = o[qs][nt][r] * nr[r];
                const unsigned u = fau(v);
                const float res = v - __uint_as_float(u & 0xffff0000u);
                dp[((G ^ s7) << 3) + e]       = (unsigned short)(u >> 16);
                dp[(((G + 4) ^ s7) << 3) + e] = (unsigned short)(fau(res) >> 16);
            }
        }
    }
}

// ---------------------------------------------------------------------------
extern "C" void kernel_launch(void* const* d_in, const int* in_sizes, int n_in,
                              void* d_out, int out_size, void* d_ws, size_t ws_size,
                              hipStream_t stream)
{
    const float* x     = (const float*)d_in[0];  // [4,2048,1024]
    const float* w_qkv = (const float*)d_in[1];  // [1024,3072]
    const float* w_out = (const float*)d_in[2];  // [1024,1024]
    const float* b_out = (const float*)d_in[3];  // [1024]
    float* out = (float*)d_out;                  // [4,2048,1024]

    // Workspace (exactly 128 MiB):
    //   q_hl 32M | k_hl 32M | vt 16M | xa_hl 32M (x pack, reused as ao pack)
    //   | wq_hl 12M | wo_hl 4M
    unsigned short* q_hl  = (unsigned short*)d_ws;
    unsigned short* k_hl  = q_hl  + (size_t)MTOT * 2048;
    unsigned short* vt    = k_hl  + (size_t)MTOT * 2048;
    unsigned short* xa_hl = vt    + (size_t)BATCH * INNER * SEQ;
    unsigned short* wq_hl = xa_hl + (size_t)32 * MTOT * 64;
    unsigned short* wo_hl = wq_hl + (size_t)32 * QKV_N * 64;

    pack_rows_hl<<<dim3(MTOT / 256, 32), 256, 0, stream>>>(x, xa_hl, MTOT, DIM);
    pack_cols_hl<<<dim3(QKV_N / 256, 32), 256, 0, stream>>>(w_qkv, wq_hl, QKV_N);
    pack_cols_hl<<<dim3(INNER / 256, 32), 256, 0, stream>>>(w_out, wo_hl, INNER);

    // 256x128 tile, 512 threads: grid (24, 32) = 768 blocks = exactly 3/CU.
    gemm_qkv_pk<<<dim3(QKV_N / 128, MTOT / 256), 512, 0, stream>>>(
        xa_hl, wq_hl, q_hl, k_hl, vt);

    // attn overwrites xa_hl (x pack no longer needed) with the packed output.
    // Grid order (h, qb, b): flat%8 = h%8 -> same-(b,h) q-blocks share an XCD.
    attn_mfma<<<dim3(HEADS, SEQ / 256, BATCH), 256, 0, stream>>>(
        q_hl, k_hl, vt, xa_hl);

    // 256 blocks = exactly 1/CU.
    gemm_out_pk<<<dim3(INNER / 128, MTOT / 256), 512, 0, stream>>>(
        xa_hl, wo_hl, b_out, out);
}

// Round 14
// 349.086 us; speedup vs baseline: 1.1861x; 1.0079x over previous
//
#include <hip/hip_runtime.h>
#include <hip/hip_bf16.h>

#define BATCH 4
#define SEQ   2048
#define DIM   1024
#define HEADS 16
#define DHEAD 64
#define INNER 1024   // HEADS*DHEAD
#define QKV_N 3072   // 3*INNER
#define MTOT  8192   // BATCH*SEQ

typedef short bf16x8 __attribute__((ext_vector_type(8)));
typedef float f32x4  __attribute__((ext_vector_type(4)));
#define MFMA16(a,b,c) __builtin_amdgcn_mfma_f32_16x16x32_bf16((a),(b),(c),0,0,0)

// log2(e) * dhead^-0.5  (scale folded into Q so softmax can use native exp2)
#define QSCALE 0.1803368801111204f

static __device__ __forceinline__ unsigned fau(float f) { return __float_as_uint(f); }
static __device__ __forceinline__ float max3f(float a, float b, float c) {
    return fmaxf(fmaxf(a, b), c);   // clang fuses to v_max3_f32
}

// Truncate-to-bf16 pack of 4 floats (hi plane). Packs 4 bf16 into uint2.
static __device__ __forceinline__ uint2 pack_hi4(float4 v) {
    return make_uint2((fau(v.x) >> 16) | (fau(v.y) & 0xffff0000u),
                      (fau(v.z) >> 16) | (fau(v.w) & 0xffff0000u));
}
static __device__ __forceinline__ float4 resid4(float4 v) {
    float4 r;
    r.x = v.x - __uint_as_float(fau(v.x) & 0xffff0000u);
    r.y = v.y - __uint_as_float(fau(v.y) & 0xffff0000u);
    r.z = v.z - __uint_as_float(fau(v.z) & 0xffff0000u);
    r.w = v.w - __uint_as_float(fau(v.w) & 0xffff0000u);
    return r;
}
static __device__ __forceinline__ uint2 pack_lo4(float4 v) { return pack_hi4(resid4(v)); }

// Packed RNE fp32->bf16 pair: dst[15:0]=bf16(a), dst[31:16]=bf16(b).
static __device__ __forceinline__ unsigned cvt_pk_bf16(float a, float b) {
    unsigned r;
    asm("v_cvt_pk_bf16_f32 %0, %1, %2" : "=v"(r) : "v"(a), "v"(b));
    return r;
}

// Workgroup barrier that drains ONLY LDS ops (lgkmcnt), not global loads
// (vmcnt): global prefetches stay in flight across the barrier.
static __device__ __forceinline__ void barrier_lgkm() {
    asm volatile("s_waitcnt lgkmcnt(0)" ::: "memory");
    __builtin_amdgcn_s_barrier();
}

// De-phase co-resident blocks.
static __device__ __forceinline__ void stagger_block() {
    const unsigned flat = blockIdx.x + gridDim.x * (blockIdx.y + gridDim.y * blockIdx.z);
    const int slot = (int)(flat % 5u);
    #pragma unroll
    for (int i = 0; i < 4; ++i)
        if (i < slot) __builtin_amdgcn_s_sleep(6);
}

// ---------------------------------------------------------------------------
// Pre-pack kernels: fp32 -> [K/32 ktiles][rows][64 shorts = hi32|lo32] with
// the (row&7) XOR granule swizzle BAKED INTO MEMORY, so GEMM staging is a
// pure linear 16B copy and fragment reads use the standard XOR formulas.
// ---------------------------------------------------------------------------
__global__ __launch_bounds__(256) void pack_rows_hl(const float* __restrict__ src,
                                                    unsigned short* __restrict__ dst,
                                                    int Mtot, int K)
{
    const int m = blockIdx.x * 256 + threadIdx.x;
    const int t = blockIdx.y;
    const float* sp = src + (size_t)m * K + t * 32;
    unsigned short buf[64];
    #pragma unroll
    for (int i = 0; i < 32; i += 4) {
        const float4 v = *(const float4*)&sp[i];
        *(uint2*)&buf[i]      = pack_hi4(v);
        *(uint2*)&buf[32 + i] = pack_lo4(v);
    }
    unsigned short* dp = dst + ((size_t)t * Mtot + m) * 64;
    const int s7 = m & 7;
    #pragma unroll
    for (int G = 0; G < 8; ++G)
        *(bf16x8*)&dp[(G ^ s7) * 8] = *(bf16x8*)&buf[G * 8];
}

__global__ __launch_bounds__(256) void pack_cols_hl(const float* __restrict__ src,
                                                    unsigned short* __restrict__ dst,
                                                    int Ntot)
{
    const int n = blockIdx.x * 256 + threadIdx.x;
    const int t = blockIdx.y;
    float vals[32];
    #pragma unroll
    for (int i = 0; i < 32; ++i) vals[i] = src[(size_t)(t * 32 + i) * Ntot + n];
    unsigned short buf[64];
    #pragma unroll
    for (int i = 0; i < 32; i += 4) {
        const float4 v = make_float4(vals[i], vals[i + 1], vals[i + 2], vals[i + 3]);
        *(uint2*)&buf[i]      = pack_hi4(v);
        *(uint2*)&buf[32 + i] = pack_lo4(v);
    }
    unsigned short* dp = dst + ((size_t)t * Ntot + n) * 64;
    const int s7 = n & 7;
    #pragma unroll
    for (int G = 0; G < 8; ++G)
        *(bf16x8*)&dp[(G ^ s7) * 8] = *(bf16x8*)&buf[G * 8];
}

// ---------------------------------------------------------------------------
// Packed bf16x3 GEMM core, 256x128 block tile, 512 threads = 8 waves
// (4M x 2N; per-wave 64x64 = the verified acc[4][4] fragment map).
// Per K-step MFMA (~1860cy) dominates LDS (~690cy) -> staging hides under
// the MFMA phase. Depth-2 write-after-read schedule, lgkmcnt-only barrier.
// (Round-11 verbatim — the session's verified best GEMM.)
// ---------------------------------------------------------------------------
static __device__ __forceinline__ void gemm_core_pk8(const unsigned short* __restrict__ Ap,
                                                     const unsigned short* __restrict__ Bp,
                                                     unsigned short* As,   // [2*256*64]
                                                     unsigned short* Bs,   // [2*128*64]
                                                     f32x4 (&acc)[4][4],
                                                     int Mtot, int Ntot, int NT,
                                                     int row0, int col0)
{
    const int tid  = threadIdx.x;
    const int lane = tid & 63;
    const int w    = tid >> 6;        // 0..7
    const int l15  = lane & 15;
    const int g    = lane >> 4;
    const int wr   = w >> 1;          // 0..3 (M)
    const int wc   = w & 1;           // 0..1 (N)

    const unsigned short* aSrc = Ap + (size_t)row0 * 64 + tid * 8;
    const unsigned short* bSrc = Bp + (size_t)col0 * 64 + tid * 8;
    const size_t aStep = (size_t)Mtot * 64;
    const size_t bStep = (size_t)Ntot * 64;

    int aoff[4][2], boff[4][2];
    #pragma unroll
    for (int mt = 0; mt < 4; ++mt) {
        const int m = wr * 64 + mt * 16 + l15;          // 0..255
        const int sw = (m & 7) << 3;
        aoff[mt][0] = m * 64 + ((g * 8) ^ sw);
        aoff[mt][1] = m * 64 + ((32 + g * 8) ^ sw);
    }
    #pragma unroll
    for (int nt = 0; nt < 4; ++nt) {
        const int n = wc * 64 + nt * 16 + l15;          // 0..127
        const int sw = (n & 7) << 3;
        boff[nt][0] = n * 64 + ((g * 8) ^ sw);
        boff[nt][1] = n * 64 + ((32 + g * 8) ^ sw);
    }

    bf16x8 ar[4], br[2];
    #pragma unroll
    for (int p = 0; p < 4; ++p) ar[p] = *(const bf16x8*)(aSrc + p * 4096);
    #pragma unroll
    for (int p = 0; p < 2; ++p) br[p] = *(const bf16x8*)(bSrc + p * 4096);
    #pragma unroll
    for (int p = 0; p < 4; ++p) *(bf16x8*)&As[tid * 8 + p * 4096] = ar[p];
    #pragma unroll
    for (int p = 0; p < 2; ++p) *(bf16x8*)&Bs[tid * 8 + p * 4096] = br[p];
    if (1 < NT) {
        #pragma unroll
        for (int p = 0; p < 4; ++p) ar[p] = *(const bf16x8*)(aSrc + aStep + p * 4096);
        #pragma unroll
        for (int p = 0; p < 2; ++p) br[p] = *(const bf16x8*)(bSrc + bStep + p * 4096);
    }
    __syncthreads();

    int cur = 0;
    for (int t = 0; t < NT; ++t) {
        const int ca = cur * 16384, cb = cur * 8192;
        bf16x8 ah[4], al[4], bh[4], bl[4];
        #pragma unroll
        for (int mt = 0; mt < 4; ++mt) {
            ah[mt] = *(const bf16x8*)&As[ca + aoff[mt][0]];
            al[mt] = *(const bf16x8*)&As[ca + aoff[mt][1]];
        }
        #pragma unroll
        for (int nt = 0; nt < 4; ++nt) {
            bh[nt] = *(const bf16x8*)&Bs[cb + boff[nt][0]];
            bl[nt] = *(const bf16x8*)&Bs[cb + boff[nt][1]];
        }
        if (t + 1 < NT) {
            const int na = (cur ^ 1) * 16384, nb = (cur ^ 1) * 8192;
            #pragma unroll
            for (int p = 0; p < 4; ++p)
                *(bf16x8*)&As[na + tid * 8 + p * 4096] = ar[p];
            #pragma unroll
            for (int p = 0; p < 2; ++p)
                *(bf16x8*)&Bs[nb + tid * 8 + p * 4096] = br[p];
        }
        if (t + 2 < NT) {
            const unsigned short* a2 = aSrc + (size_t)(t + 2) * aStep;
            const unsigned short* b2 = bSrc + (size_t)(t + 2) * bStep;
            #pragma unroll
            for (int p = 0; p < 4; ++p) ar[p] = *(const bf16x8*)(a2 + p * 4096);
            #pragma unroll
            for (int p = 0; p < 2; ++p) br[p] = *(const bf16x8*)(b2 + p * 4096);
        }
        #pragma unroll
        for (int mt = 0; mt < 4; ++mt)
            #pragma unroll
            for (int nt = 0; nt < 4; ++nt) {
                acc[mt][nt] = MFMA16(ah[mt], bh[nt], acc[mt][nt]);
                acc[mt][nt] = MFMA16(ah[mt], bl[nt], acc[mt][nt]);
                acc[mt][nt] = MFMA16(al[mt], bh[nt], acc[mt][nt]);
            }
        barrier_lgkm();
        cur ^= 1;
    }
}

// ---------------------------------------------------------------------------
// Out-projection GEMM: packed A (from attn) x packed w_out -> fp32 + bias.
// ---------------------------------------------------------------------------
__global__ __launch_bounds__(512, 2) void gemm_out_pk(const unsigned short* __restrict__ Ap,
                                                      const unsigned short* __restrict__ Bp,
                                                      const float* __restrict__ bias,
                                                      float* __restrict__ C)
{
    __shared__ unsigned short As[2 * 256 * 64];
    __shared__ unsigned short Bs[2 * 128 * 64];

    const int tid  = threadIdx.x;
    const int lane = tid & 63;
    const int w    = tid >> 6;
    const int l15  = lane & 15;
    const int g    = lane >> 4;
    const int wr   = w >> 1, wc = w & 1;
    const int row0 = blockIdx.y * 256, col0 = blockIdx.x * 128;

    f32x4 acc[4][4] = {};
    gemm_core_pk8(Ap, Bp, As, Bs, acc, MTOT, INNER, 32, row0, col0);

    #pragma unroll
    for (int nt = 0; nt < 4; ++nt) {
        const int c = col0 + wc * 64 + nt * 16 + l15;
        const float bv = bias[c];
        #pragma unroll
        for (int mt = 0; mt < 4; ++mt)
            #pragma unroll
            for (int r = 0; r < 4; ++r) {
                const int rr = row0 + wr * 64 + mt * 16 + g * 4 + r;
                C[(size_t)rr * INNER + c] = acc[mt][nt][r] + bv;
            }
    }
}

// ---------------------------------------------------------------------------
// QKV GEMM: 8-wave core + attention-ready epilogue (q/k hi-lo planes,
// V transposed + pi-permuted RN bf16).
// ---------------------------------------------------------------------------
__global__ __launch_bounds__(512, 2) void gemm_qkv_pk(const unsigned short* __restrict__ Ap,
                                                      const unsigned short* __restrict__ Bp,
                                                      unsigned short* __restrict__ q_hl,
                                                      unsigned short* __restrict__ k_hl,
                                                      unsigned short* __restrict__ vt)
{
    __shared__ unsigned short As[2 * 256 * 64];
    __shared__ unsigned short Bs[2 * 128 * 64];

    const int tid  = threadIdx.x;
    const int lane = tid & 63;
    const int w    = tid >> 6;
    const int l15  = lane & 15;
    const int g    = lane >> 4;
    const int wr   = w >> 1, wc = w & 1;
    const int row0 = blockIdx.y * 256, col0 = blockIdx.x * 128;

    f32x4 acc[4][4] = {};
    gemm_core_pk8(Ap, Bp, As, Bs, acc, MTOT, QKV_N, 32, row0, col0);

    if (col0 < 2 * INNER) {
        unsigned short* plane = (col0 < INNER) ? q_hl : k_hl;
        const float sc = (col0 < INNER) ? QSCALE : 1.0f;
        #pragma unroll
        for (int nt = 0; nt < 4; ++nt) {
            const int c  = col0 + wc * 64 + nt * 16 + l15;
            const int cc = c & (INNER - 1);
            const int hd = (cc >> 6) * 128 + (cc & 63);
            #pragma unroll
            for (int mt = 0; mt < 4; ++mt)
                #pragma unroll
                for (int r = 0; r < 4; ++r) {
                    const int rr = row0 + wr * 64 + mt * 16 + g * 4 + r;
                    const float v = acc[mt][nt][r] * sc;
                    const unsigned u = fau(v);
                    const float res = v - __uint_as_float(u & 0xffff0000u);
                    unsigned short* dp = plane + (size_t)rr * 2048 + hd;
                    dp[0]  = (unsigned short)(u >> 16);
                    dp[64] = (unsigned short)(fau(res) >> 16);
                }
        }
    } else {
        #pragma unroll
        for (int nt = 0; nt < 4; ++nt) {
            const int f = col0 + wc * 64 + nt * 16 + l15 - 2 * INNER;  // h*64+d
            #pragma unroll
            for (int mt = 0; mt < 4; ++mt) {
                const int rr0 = row0 + wr * 64 + mt * 16 + g * 4;      // token, %4==0
                const int bb  = rr0 >> 11;
                const int n   = rr0 & (SEQ - 1);
                const int pn  = (n & ~31) | ((n & 12) << 1) | ((n & 16) >> 2);
                const uint2 pk = make_uint2(
                    cvt_pk_bf16(acc[mt][nt][0], acc[mt][nt][1]),
                    cvt_pk_bf16(acc[mt][nt][2], acc[mt][nt][3]));
                *(uint2*)&vt[((size_t)bb * INNER + f) * SEQ + pn] = pk;
            }
        }
    }
}

// ---------------------------------------------------------------------------
// MFMA flash attention, 4 q-sets/wave (round-11 structure, verified best:
// 2-buf K/V, lgkmcnt barrier, stagger, setprio, softmax-then-PV).
// Micro-change vs round 11: balanced max3 tree (depth 3 vs serial chain
// depth 8; max is associative -> bit-identical) and pairwise sum tree
// (fp32 reassociation, ~1e-7 perturbation, invisible at bf16 tolerance).
// ---------------------------------------------------------------------------
__global__ __launch_bounds__(256, 2) void attn_mfma(const unsigned short* __restrict__ q_hl,
                                                    const unsigned short* __restrict__ k_hl,
                                                    const unsigned short* __restrict__ vt,
                                                    unsigned short* __restrict__ ao_hl)
{
    __shared__ unsigned short Ks[2 * 64 * 128];  // double-buffered, XOR-swizzled
    __shared__ unsigned short Vs[2 * 64 * 64];

    stagger_block();

    const int tid  = threadIdx.x;
    const int lane = tid & 63;
    const int w    = tid >> 6;
    const int l15  = lane & 15;
    const int g    = lane >> 4;
    const int h  = blockIdx.x, qb = blockIdx.y, b = blockIdx.z;
    const int q0 = qb * 256 + w * 64;

    // Q fragments (B-operand layout: lane holds Q[q][kk*32+8g..+8], hi+lo).
    bf16x8 qh[4][2], ql[4][2];
    #pragma unroll
    for (int qs = 0; qs < 4; ++qs) {
        const unsigned short* qp =
            q_hl + (size_t)(b * SEQ + q0 + qs * 16 + l15) * 2048 + h * 128;
        #pragma unroll
        for (int kk = 0; kk < 2; ++kk) {
            qh[qs][kk] = *(const bf16x8*)&qp[kk * 32 + g * 8];
            ql[qs][kk] = *(const bf16x8*)&qp[64 + kk * 32 + g * 8];
        }
    }

    f32x4 o[4][4] = {};                    // [qs][nt]: O[q=4g+r][d=nt*16+l15]
    float m_run[4] = {-1e30f, -1e30f, -1e30f, -1e30f};
    float l_run[4] = {0.f, 0.f, 0.f, 0.f};

    // Staging address precompute (pure copies; all swizzle math hoisted).
    const int kj   = tid >> 4;                         // K row within 16-row pass
    const int ko8  = (tid & 15) * 8;
    const int kdst = kj * 128 + (ko8 ^ (kj << 3));
    const unsigned short* ksrc =
        k_hl + ((size_t)(b * SEQ + kj)) * 2048 + h * 128 + ko8;

    const int vd   = tid >> 3;                         // V row within 32-row pass
    const int vu8  = (tid & 7) * 8;
    const int vdst = vd * 64 + (vu8 ^ ((vd & 7) << 3));
    const unsigned short* vsrc =
        vt + ((size_t)(b * HEADS + h) * 64 + vd) * SEQ + vu8;

    // Fragment read offsets.
    const int krow = l15 * 128;
    int koff[2][2];
    #pragma unroll
    for (int kk = 0; kk < 2; ++kk) {
        koff[kk][0] = (kk * 32 + g * 8) ^ (l15 * 8);
        koff[kk][1] = (64 + kk * 32 + g * 8) ^ (l15 * 8);
    }
    const int vrow = l15 * 64;
    const int voff[2] = { (g * 8) ^ ((l15 & 7) * 8), (32 + g * 8) ^ ((l15 & 7) * 8) };

    // Prologue: prefetch tile 0 into regs.
    bf16x8 kr[4], vr[2];
    #pragma unroll
    for (int p = 0; p < 4; ++p)
        kr[p] = *(const bf16x8*)&ksrc[(size_t)(p * 16) * 2048];
    #pragma unroll
    for (int p = 0; p < 2; ++p)
        vr[p] = *(const bf16x8*)&vsrc[(size_t)p * 32 * SEQ];

    int cur = 0;
    for (int kv = 0; kv < SEQ / 64; ++kv) {
        // Write prefetched tile into buf[cur]; lgkmcnt-only barrier orders
        // buffer reuse without draining the global prefetch queue.
        const int kb = cur * 8192, vb = cur * 4096;
        #pragma unroll
        for (int p = 0; p < 4; ++p)
            *(bf16x8*)&Ks[kb + p * 2048 + kdst] = kr[p];
        #pragma unroll
        for (int p = 0; p < 2; ++p)
            *(bf16x8*)&Vs[vb + p * 2048 + vdst] = vr[p];
        barrier_lgkm();
        if (kv + 1 < SEQ / 64) {
            const int j0n = (kv + 1) * 64;
            #pragma unroll
            for (int p = 0; p < 4; ++p)
                kr[p] = *(const bf16x8*)&ksrc[(size_t)(j0n + p * 16) * 2048];
            #pragma unroll
            for (int p = 0; p < 2; ++p)
                vr[p] = *(const bf16x8*)&vsrc[(size_t)p * 32 * SEQ + j0n];
        }

        // QK^T (swapped, bf16x3): each K fragment read feeds all 4 q-sets.
        f32x4 s[4][4] = {};
        __builtin_amdgcn_s_setprio(1);
        #pragma unroll
        for (int jt = 0; jt < 4; ++jt) {
            #pragma unroll
            for (int kk = 0; kk < 2; ++kk) {
                const bf16x8 khf = *(const bf16x8*)&Ks[kb + jt * 2048 + krow + koff[kk][0]];
                const bf16x8 klf = *(const bf16x8*)&Ks[kb + jt * 2048 + krow + koff[kk][1]];
                #pragma unroll
                for (int qs = 0; qs < 4; ++qs) {
                    s[qs][jt] = MFMA16(khf, qh[qs][kk], s[qs][jt]);
                    s[qs][jt] = MFMA16(khf, ql[qs][kk], s[qs][jt]);
                    s[qs][jt] = MFMA16(klf, qh[qs][kk], s[qs][jt]);
                }
            }
        }
        __builtin_amdgcn_s_setprio(0);

        // Online softmax (log2 domain, defer-max) + packed P, per q-set.
        bf16x8 pav[4][2];
        #pragma unroll
        for (int qs = 0; qs < 4; ++qs) {
            const f32x4* sq = s[qs];
            // Balanced max3 tree, depth 3 (max associative -> bit-identical).
            const float t0 = max3f(sq[0][0], sq[0][1], sq[0][2]);
            const float t1 = max3f(sq[0][3], sq[1][0], sq[1][1]);
            const float t2 = max3f(sq[1][2], sq[1][3], sq[2][0]);
            const float t3 = max3f(sq[2][1], sq[2][2], sq[2][3]);
            const float t4 = max3f(sq[3][0], sq[3][1], sq[3][2]);
            float mx = fmaxf(max3f(t0, t1, t2), max3f(t3, t4, sq[3][3]));
            mx = fmaxf(mx, __shfl_xor(mx, 16));
            mx = fmaxf(mx, __shfl_xor(mx, 32));
            // Defer-max: rescale only if some q-row's max grew past m_run+8.
            if (!__all(mx - m_run[qs] <= 8.f)) {
                const float mnew = fmaxf(m_run[qs], mx);
                const float corr = __builtin_amdgcn_exp2f(m_run[qs] - mnew);
                m_run[qs] = mnew;
                l_run[qs] *= corr;
                const float cr0 = __shfl(corr, g * 4 + 0);
                const float cr1 = __shfl(corr, g * 4 + 1);
                const float cr2 = __shfl(corr, g * 4 + 2);
                const float cr3 = __shfl(corr, g * 4 + 3);
                #pragma unroll
                for (int nt = 0; nt < 4; ++nt) {
                    o[qs][nt][0] *= cr0; o[qs][nt][1] *= cr1;
                    o[qs][nt][2] *= cr2; o[qs][nt][3] *= cr3;
                }
            }
            // exp2 + pairwise sum tree (depth 4).
            float ps[4];
            #pragma unroll
            for (int jt = 0; jt < 4; ++jt) {
                float e0 = __builtin_amdgcn_exp2f(sq[jt][0] - m_run[qs]);
                float e1 = __builtin_amdgcn_exp2f(sq[jt][1] - m_run[qs]);
                float e2 = __builtin_amdgcn_exp2f(sq[jt][2] - m_run[qs]);
                float e3 = __builtin_amdgcn_exp2f(sq[jt][3] - m_run[qs]);
                s[qs][jt][0] = e0; s[qs][jt][1] = e1;
                s[qs][jt][2] = e2; s[qs][jt][3] = e3;
                ps[jt] = (e0 + e1) + (e2 + e3);
            }
            float sm = (ps[0] + ps[1]) + (ps[2] + ps[3]);
            sm += __shfl_xor(sm, 16);
            sm += __shfl_xor(sm, 32);
            l_run[qs] += sm;

            #pragma unroll
            for (int t = 0; t < 2; ++t) {
                union { uint2 u[2]; bf16x8 v; } P;
                P.u[0] = make_uint2(cvt_pk_bf16(s[qs][2 * t][0],     s[qs][2 * t][1]),
                                    cvt_pk_bf16(s[qs][2 * t][2],     s[qs][2 * t][3]));
                P.u[1] = make_uint2(cvt_pk_bf16(s[qs][2 * t + 1][0], s[qs][2 * t + 1][1]),
                                    cvt_pk_bf16(s[qs][2 * t + 1][2], s[qs][2 * t + 1][3]));
                pav[qs][t] = P.v;
            }
        }

        // PV: one b128 V read per (t,nt), shared across all 4 q-sets.
        __builtin_amdgcn_s_setprio(1);
        #pragma unroll
        for (int t = 0; t < 2; ++t)
            #pragma unroll
            for (int nt = 0; nt < 4; ++nt) {
                const bf16x8 vbv = *(const bf16x8*)&Vs[vb + nt * 1024 + vrow + voff[t]];
                #pragma unroll
                for (int qs = 0; qs < 4; ++qs)
                    o[qs][nt] = MFMA16(pav[qs][t], vbv, o[qs][nt]);
            }
        __builtin_amdgcn_s_setprio(0);
        cur ^= 1;
    }

    // Epilogue: normalize by 1/l per O-row and store PACKED hi/lo into
    // ao_hl[ktile][M][64] with the (M&7) granule swizzle baked in.
    #pragma unroll
    for (int qs = 0; qs < 4; ++qs) {
        const float il = 1.f / l_run[qs];
        const float nr0 = __shfl(il, g * 4 + 0);
        const float nr1 = __shfl(il, g * 4 + 1);
        const float nr2 = __shfl(il, g * 4 + 2);
        const float nr3 = __shfl(il, g * 4 + 3);
        const float nr[4] = {nr0, nr1, nr2, nr3};
        #pragma unroll
        for (int nt = 0; nt < 4; ++nt) {
            const int k  = h * DHEAD + nt * 16 + l15;
            const int t  = k >> 5;
            const int kk = k & 31;
            const int G  = kk >> 3;   // 0..3
            const int e  = kk & 7;
            #pragma unroll
            for (int r = 0; r < 4; ++r) {
                const int M  = b * SEQ + q0 + qs * 16 + g * 4 + r;
                const int s7 = M & 7;
                unsigned short* dp = ao_hl + ((size_t)t * MTOT + M) * 64;
                const float v = o[qs][nt][r] * nr[r];
                const unsigned u = fau(v);
                const float res = v - __uint_as_float(u & 0xffff0000u);
                dp[((G ^ s7) << 3) + e]       = (unsigned short)(u >> 16);
                dp[(((G + 4) ^ s7) << 3) + e] = (unsigned short)(fau(res) >> 16);
            }
        }
    }
}

// ---------------------------------------------------------------------------
extern "C" void kernel_launch(void* const* d_in, const int* in_sizes, int n_in,
                              void* d_out, int out_size, void* d_ws, size_t ws_size,
                              hipStream_t stream)
{
    const float* x     = (const float*)d_in[0];  // [4,2048,1024]
    const float* w_qkv = (const float*)d_in[1];  // [1024,3072]
    const float* w_out = (const float*)d_in[2];  // [1024,1024]
    const float* b_out = (const float*)d_in[3];  // [1024]
    float* out = (float*)d_out;                  // [4,2048,1024]

    // Workspace (exactly 128 MiB):
    //   q_hl 32M | k_hl 32M | vt 16M | xa_hl 32M (x pack, reused as ao pack)
    //   | wq_hl 12M | wo_hl 4M
    unsigned short* q_hl  = (unsigned short*)d_ws;
    unsigned short* k_hl  = q_hl  + (size_t)MTOT * 2048;
    unsigned short* vt    = k_hl  + (size_t)MTOT * 2048;
    unsigned short* xa_hl = vt    + (size_t)BATCH * INNER * SEQ;
    unsigned short* wq_hl = xa_hl + (size_t)32 * MTOT * 64;
    unsigned short* wo_hl = wq_hl + (size_t)32 * QKV_N * 64;

    pack_rows_hl<<<dim3(MTOT / 256, 32), 256, 0, stream>>>(x, xa_hl, MTOT, DIM);
    pack_cols_hl<<<dim3(QKV_N / 256, 32), 256, 0, stream>>>(w_qkv, wq_hl, QKV_N);
    pack_cols_hl<<<dim3(INNER / 256, 32), 256, 0, stream>>>(w_out, wo_hl, INNER);

    // 256x128 tile, 512 threads: grid (24, 32) = 768 blocks = exactly 3/CU.
    gemm_qkv_pk<<<dim3(QKV_N / 128, MTOT / 256), 512, 0, stream>>>(
        xa_hl, wq_hl, q_hl, k_hl, vt);

    // attn overwrites xa_hl (x pack no longer needed) with the packed output.
    // Grid order (h, qb, b): flat%8 = h%8 -> same-(b,h) q-blocks share an XCD.
    attn_mfma<<<dim3(HEADS, SEQ / 256, BATCH), 256, 0, stream>>>(
        q_hl, k_hl, vt, xa_hl);

    // 256 blocks = exactly 1/CU.
    gemm_out_pk<<<dim3(INNER / 128, MTOT / 256), 512, 0, stream>>>(
        xa_hl, wo_hl, b_out, out);
}

// Round 15
// 340.997 us; speedup vs baseline: 1.2142x; 1.0237x over previous
//
#include <hip/hip_runtime.h>
#include <hip/hip_bf16.h>

#define BATCH 4
#define SEQ   2048
#define DIM   1024
#define HEADS 16
#define DHEAD 64
#define INNER 1024   // HEADS*DHEAD
#define QKV_N 3072   // 3*INNER
#define MTOT  8192   // BATCH*SEQ

typedef short bf16x8 __attribute__((ext_vector_type(8)));
typedef float f32x4  __attribute__((ext_vector_type(4)));
#define MFMA16(a,b,c) __builtin_amdgcn_mfma_f32_16x16x32_bf16((a),(b),(c),0,0,0)

// log2(e) * dhead^-0.5  (scale folded into Q so softmax can use native exp2)
#define QSCALE 0.1803368801111204f

static __device__ __forceinline__ unsigned fau(float f) { return __float_as_uint(f); }
static __device__ __forceinline__ float max3f(float a, float b, float c) {
    return fmaxf(fmaxf(a, b), c);   // clang fuses to v_max3_f32
}

// Truncate-to-bf16 pack of 4 floats (hi plane). Packs 4 bf16 into uint2.
static __device__ __forceinline__ uint2 pack_hi4(float4 v) {
    return make_uint2((fau(v.x) >> 16) | (fau(v.y) & 0xffff0000u),
                      (fau(v.z) >> 16) | (fau(v.w) & 0xffff0000u));
}
static __device__ __forceinline__ float4 resid4(float4 v) {
    float4 r;
    r.x = v.x - __uint_as_float(fau(v.x) & 0xffff0000u);
    r.y = v.y - __uint_as_float(fau(v.y) & 0xffff0000u);
    r.z = v.z - __uint_as_float(fau(v.z) & 0xffff0000u);
    r.w = v.w - __uint_as_float(fau(v.w) & 0xffff0000u);
    return r;
}
static __device__ __forceinline__ uint2 pack_lo4(float4 v) { return pack_hi4(resid4(v)); }

// Packed RNE fp32->bf16 pair: dst[15:0]=bf16(a), dst[31:16]=bf16(b).
static __device__ __forceinline__ unsigned cvt_pk_bf16(float a, float b) {
    unsigned r;
    asm("v_cvt_pk_bf16_f32 %0, %1, %2" : "=v"(r) : "v"(a), "v"(b));
    return r;
}

// Workgroup barrier that drains ONLY LDS ops (lgkmcnt), not global loads
// (vmcnt): global prefetches stay in flight across the barrier.
static __device__ __forceinline__ void barrier_lgkm() {
    asm volatile("s_waitcnt lgkmcnt(0)" ::: "memory");
    __builtin_amdgcn_s_barrier();
}

// De-phase co-resident blocks.
static __device__ __forceinline__ void stagger_block() {
    const unsigned flat = blockIdx.x + gridDim.x * (blockIdx.y + gridDim.y * blockIdx.z);
    const int slot = (int)(flat % 5u);
    #pragma unroll
    for (int i = 0; i < 4; ++i)
        if (i < slot) __builtin_amdgcn_s_sleep(6);
}

// ---------------------------------------------------------------------------
// Pre-pack kernels: fp32 -> [K/32 ktiles][rows][64 shorts = hi32|lo32] with
// the (row&7) XOR granule swizzle BAKED INTO MEMORY, so GEMM staging is a
// pure linear 16B copy and fragment reads use the standard XOR formulas.
// ---------------------------------------------------------------------------
__global__ __launch_bounds__(256) void pack_rows_hl(const float* __restrict__ src,
                                                    unsigned short* __restrict__ dst,
                                                    int Mtot, int K)
{
    const int m = blockIdx.x * 256 + threadIdx.x;
    const int t = blockIdx.y;
    const float* sp = src + (size_t)m * K + t * 32;
    unsigned short buf[64];
    #pragma unroll
    for (int i = 0; i < 32; i += 4) {
        const float4 v = *(const float4*)&sp[i];
        *(uint2*)&buf[i]      = pack_hi4(v);
        *(uint2*)&buf[32 + i] = pack_lo4(v);
    }
    unsigned short* dp = dst + ((size_t)t * Mtot + m) * 64;
    const int s7 = m & 7;
    #pragma unroll
    for (int G = 0; G < 8; ++G)
        *(bf16x8*)&dp[(G ^ s7) * 8] = *(bf16x8*)&buf[G * 8];
}

__global__ __launch_bounds__(256) void pack_cols_hl(const float* __restrict__ src,
                                                    unsigned short* __restrict__ dst,
                                                    int Ntot)
{
    const int n = blockIdx.x * 256 + threadIdx.x;
    const int t = blockIdx.y;
    float vals[32];
    #pragma unroll
    for (int i = 0; i < 32; ++i) vals[i] = src[(size_t)(t * 32 + i) * Ntot + n];
    unsigned short buf[64];
    #pragma unroll
    for (int i = 0; i < 32; i += 4) {
        const float4 v = make_float4(vals[i], vals[i + 1], vals[i + 2], vals[i + 3]);
        *(uint2*)&buf[i]      = pack_hi4(v);
        *(uint2*)&buf[32 + i] = pack_lo4(v);
    }
    unsigned short* dp = dst + ((size_t)t * Ntot + n) * 64;
    const int s7 = n & 7;
    #pragma unroll
    for (int G = 0; G < 8; ++G)
        *(bf16x8*)&dp[(G ^ s7) * 8] = *(bf16x8*)&buf[G * 8];
}

// ---------------------------------------------------------------------------
// Packed bf16x3 GEMM core, 256x128 block tile, 512 threads = 8 waves
// (4M x 2N; per-wave 64x64 = the verified acc[4][4] fragment map).
// Per K-step MFMA (~1860cy) dominates LDS (~690cy) -> staging hides under
// the MFMA phase. Depth-2 write-after-read schedule, lgkmcnt-only barrier.
// (Round-11 verbatim — the session's verified best GEMM.)
// ---------------------------------------------------------------------------
static __device__ __forceinline__ void gemm_core_pk8(const unsigned short* __restrict__ Ap,
                                                     const unsigned short* __restrict__ Bp,
                                                     unsigned short* As,   // [2*256*64]
                                                     unsigned short* Bs,   // [2*128*64]
                                                     f32x4 (&acc)[4][4],
                                                     int Mtot, int Ntot, int NT,
                                                     int row0, int col0)
{
    const int tid  = threadIdx.x;
    const int lane = tid & 63;
    const int w    = tid >> 6;        // 0..7
    const int l15  = lane & 15;
    const int g    = lane >> 4;
    const int wr   = w >> 1;          // 0..3 (M)
    const int wc   = w & 1;           // 0..1 (N)

    const unsigned short* aSrc = Ap + (size_t)row0 * 64 + tid * 8;
    const unsigned short* bSrc = Bp + (size_t)col0 * 64 + tid * 8;
    const size_t aStep = (size_t)Mtot * 64;
    const size_t bStep = (size_t)Ntot * 64;

    int aoff[4][2], boff[4][2];
    #pragma unroll
    for (int mt = 0; mt < 4; ++mt) {
        const int m = wr * 64 + mt * 16 + l15;          // 0..255
        const int sw = (m & 7) << 3;
        aoff[mt][0] = m * 64 + ((g * 8) ^ sw);
        aoff[mt][1] = m * 64 + ((32 + g * 8) ^ sw);
    }
    #pragma unroll
    for (int nt = 0; nt < 4; ++nt) {
        const int n = wc * 64 + nt * 16 + l15;          // 0..127
        const int sw = (n & 7) << 3;
        boff[nt][0] = n * 64 + ((g * 8) ^ sw);
        boff[nt][1] = n * 64 + ((32 + g * 8) ^ sw);
    }

    bf16x8 ar[4], br[2];
    #pragma unroll
    for (int p = 0; p < 4; ++p) ar[p] = *(const bf16x8*)(aSrc + p * 4096);
    #pragma unroll
    for (int p = 0; p < 2; ++p) br[p] = *(const bf16x8*)(bSrc + p * 4096);
    #pragma unroll
    for (int p = 0; p < 4; ++p) *(bf16x8*)&As[tid * 8 + p * 4096] = ar[p];
    #pragma unroll
    for (int p = 0; p < 2; ++p) *(bf16x8*)&Bs[tid * 8 + p * 4096] = br[p];
    if (1 < NT) {
        #pragma unroll
        for (int p = 0; p < 4; ++p) ar[p] = *(const bf16x8*)(aSrc + aStep + p * 4096);
        #pragma unroll
        for (int p = 0; p < 2; ++p) br[p] = *(const bf16x8*)(bSrc + bStep + p * 4096);
    }
    __syncthreads();

    int cur = 0;
    for (int t = 0; t < NT; ++t) {
        const int ca = cur * 16384, cb = cur * 8192;
        bf16x8 ah[4], al[4], bh[4], bl[4];
        #pragma unroll
        for (int mt = 0; mt < 4; ++mt) {
            ah[mt] = *(const bf16x8*)&As[ca + aoff[mt][0]];
            al[mt] = *(const bf16x8*)&As[ca + aoff[mt][1]];
        }
        #pragma unroll
        for (int nt = 0; nt < 4; ++nt) {
            bh[nt] = *(const bf16x8*)&Bs[cb + boff[nt][0]];
            bl[nt] = *(const bf16x8*)&Bs[cb + boff[nt][1]];
        }
        if (t + 1 < NT) {
            const int na = (cur ^ 1) * 16384, nb = (cur ^ 1) * 8192;
            #pragma unroll
            for (int p = 0; p < 4; ++p)
                *(bf16x8*)&As[na + tid * 8 + p * 4096] = ar[p];
            #pragma unroll
            for (int p = 0; p < 2; ++p)
                *(bf16x8*)&Bs[nb + tid * 8 + p * 4096] = br[p];
        }
        if (t + 2 < NT) {
            const unsigned short* a2 = aSrc + (size_t)(t + 2) * aStep;
            const unsigned short* b2 = bSrc + (size_t)(t + 2) * bStep;
            #pragma unroll
            for (int p = 0; p < 4; ++p) ar[p] = *(const bf16x8*)(a2 + p * 4096);
            #pragma unroll
            for (int p = 0; p < 2; ++p) br[p] = *(const bf16x8*)(b2 + p * 4096);
        }
        #pragma unroll
        for (int mt = 0; mt < 4; ++mt)
            #pragma unroll
            for (int nt = 0; nt < 4; ++nt) {
                acc[mt][nt] = MFMA16(ah[mt], bh[nt], acc[mt][nt]);
                acc[mt][nt] = MFMA16(ah[mt], bl[nt], acc[mt][nt]);
                acc[mt][nt] = MFMA16(al[mt], bh[nt], acc[mt][nt]);
            }
        barrier_lgkm();
        cur ^= 1;
    }
}

// ---------------------------------------------------------------------------
// Out-projection GEMM: packed A (from attn) x packed w_out -> fp32 + bias.
// Grid (INNER/128, MTOT/256) = 256 blocks = exactly 1/CU.
// ---------------------------------------------------------------------------
__global__ __launch_bounds__(512, 2) void gemm_out_pk(const unsigned short* __restrict__ Ap,
                                                      const unsigned short* __restrict__ Bp,
                                                      const float* __restrict__ bias,
                                                      float* __restrict__ C)
{
    __shared__ unsigned short As[2 * 256 * 64];
    __shared__ unsigned short Bs[2 * 128 * 64];

    const int tid  = threadIdx.x;
    const int lane = tid & 63;
    const int w    = tid >> 6;
    const int l15  = lane & 15;
    const int g    = lane >> 4;
    const int wr   = w >> 1, wc = w & 1;
    const int row0 = blockIdx.y * 256, col0 = blockIdx.x * 128;

    f32x4 acc[4][4] = {};
    gemm_core_pk8(Ap, Bp, As, Bs, acc, MTOT, INNER, 32, row0, col0);

    #pragma unroll
    for (int nt = 0; nt < 4; ++nt) {
        const int c = col0 + wc * 64 + nt * 16 + l15;
        const float bv = bias[c];
        #pragma unroll
        for (int mt = 0; mt < 4; ++mt)
            #pragma unroll
            for (int r = 0; r < 4; ++r) {
                const int rr = row0 + wr * 64 + mt * 16 + g * 4 + r;
                C[(size_t)rr * INNER + c] = acc[mt][nt][r] + bv;
            }
    }
}

// ---------------------------------------------------------------------------
// QKV GEMM: 8-wave core + attention-ready epilogue (q/k hi-lo planes,
// V transposed + pi-permuted RN bf16).
// ---------------------------------------------------------------------------
__global__ __launch_bounds__(512, 2) void gemm_qkv_pk(const unsigned short* __restrict__ Ap,
                                                      const unsigned short* __restrict__ Bp,
                                                      unsigned short* __restrict__ q_hl,
                                                      unsigned short* __restrict__ k_hl,
                                                      unsigned short* __restrict__ vt)
{
    __shared__ unsigned short As[2 * 256 * 64];
    __shared__ unsigned short Bs[2 * 128 * 64];

    const int tid  = threadIdx.x;
    const int lane = tid & 63;
    const int w    = tid >> 6;
    const int l15  = lane & 15;
    const int g    = lane >> 4;
    const int wr   = w >> 1, wc = w & 1;
    const int row0 = blockIdx.y * 256, col0 = blockIdx.x * 128;

    f32x4 acc[4][4] = {};
    gemm_core_pk8(Ap, Bp, As, Bs, acc, MTOT, QKV_N, 32, row0, col0);

    if (col0 < 2 * INNER) {
        unsigned short* plane = (col0 < INNER) ? q_hl : k_hl;
        const float sc = (col0 < INNER) ? QSCALE : 1.0f;
        #pragma unroll
        for (int nt = 0; nt < 4; ++nt) {
            const int c  = col0 + wc * 64 + nt * 16 + l15;
            const int cc = c & (INNER - 1);
            const int hd = (cc >> 6) * 128 + (cc & 63);
            #pragma unroll
            for (int mt = 0; mt < 4; ++mt)
                #pragma unroll
                for (int r = 0; r < 4; ++r) {
                    const int rr = row0 + wr * 64 + mt * 16 + g * 4 + r;
                    const float v = acc[mt][nt][r] * sc;
                    const unsigned u = fau(v);
                    const float res = v - __uint_as_float(u & 0xffff0000u);
                    unsigned short* dp = plane + (size_t)rr * 2048 + hd;
                    dp[0]  = (unsigned short)(u >> 16);
                    dp[64] = (unsigned short)(fau(res) >> 16);
                }
        }
    } else {
        #pragma unroll
        for (int nt = 0; nt < 4; ++nt) {
            const int f = col0 + wc * 64 + nt * 16 + l15 - 2 * INNER;  // h*64+d
            #pragma unroll
            for (int mt = 0; mt < 4; ++mt) {
                const int rr0 = row0 + wr * 64 + mt * 16 + g * 4;      // token, %4==0
                const int bb  = rr0 >> 11;
                const int n   = rr0 & (SEQ - 1);
                const int pn  = (n & ~31) | ((n & 12) << 1) | ((n & 16) >> 2);
                const uint2 pk = make_uint2(
                    cvt_pk_bf16(acc[mt][nt][0], acc[mt][nt][1]),
                    cvt_pk_bf16(acc[mt][nt][2], acc[mt][nt][3]));
                *(uint2*)&vt[((size_t)bb * INNER + f) * SEQ + pn] = pk;
            }
        }
    }
}

// ---------------------------------------------------------------------------
// MFMA flash attention, 4 q-sets/wave (round-11 version, verified best):
//  - grid (h, qb, b): flat%8 = h%8 -> same-(b,h) q-blocks share an XCD.
//  - double-buffered K/V LDS, lgkmcnt-only barrier/iter; next tile's global
//    loads issued right after the barrier, landing under MFMA+softmax.
//  - v_max3 reduction chains; s_setprio(1) around MFMA clusters.
//  - epilogue stores packed hi/lo so the out-proj GEMM reads fragments.
// ---------------------------------------------------------------------------
__global__ __launch_bounds__(256, 2) void attn_mfma(const unsigned short* __restrict__ q_hl,
                                                    const unsigned short* __restrict__ k_hl,
                                                    const unsigned short* __restrict__ vt,
                                                    unsigned short* __restrict__ ao_hl)
{
    __shared__ unsigned short Ks[2 * 64 * 128];  // double-buffered, XOR-swizzled
    __shared__ unsigned short Vs[2 * 64 * 64];

    stagger_block();

    const int tid  = threadIdx.x;
    const int lane = tid & 63;
    const int w    = tid >> 6;
    const int l15  = lane & 15;
    const int g    = lane >> 4;
    const int h  = blockIdx.x, qb = blockIdx.y, b = blockIdx.z;
    const int q0 = qb * 256 + w * 64;

    // Q fragments (B-operand layout: lane holds Q[q][kk*32+8g..+8], hi+lo).
    bf16x8 qh[4][2], ql[4][2];
    #pragma unroll
    for (int qs = 0; qs < 4; ++qs) {
        const unsigned short* qp =
            q_hl + (size_t)(b * SEQ + q0 + qs * 16 + l15) * 2048 + h * 128;
        #pragma unroll
        for (int kk = 0; kk < 2; ++kk) {
            qh[qs][kk] = *(const bf16x8*)&qp[kk * 32 + g * 8];
            ql[qs][kk] = *(const bf16x8*)&qp[64 + kk * 32 + g * 8];
        }
    }

    f32x4 o[4][4] = {};                    // [qs][nt]: O[q=4g+r][d=nt*16+l15]
    float m_run[4] = {-1e30f, -1e30f, -1e30f, -1e30f};
    float l_run[4] = {0.f, 0.f, 0.f, 0.f};

    // Staging address precompute (pure copies; all swizzle math hoisted).
    const int kj   = tid >> 4;                         // K row within 16-row pass
    const int ko8  = (tid & 15) * 8;
    const int kdst = kj * 128 + (ko8 ^ (kj << 3));
    const unsigned short* ksrc =
        k_hl + ((size_t)(b * SEQ + kj)) * 2048 + h * 128 + ko8;

    const int vd   = tid >> 3;                         // V row within 32-row pass
    const int vu8  = (tid & 7) * 8;
    const int vdst = vd * 64 + (vu8 ^ ((vd & 7) << 3));
    const unsigned short* vsrc =
        vt + ((size_t)(b * HEADS + h) * 64 + vd) * SEQ + vu8;

    // Fragment read offsets.
    const int krow = l15 * 128;
    int koff[2][2];
    #pragma unroll
    for (int kk = 0; kk < 2; ++kk) {
        koff[kk][0] = (kk * 32 + g * 8) ^ (l15 * 8);
        koff[kk][1] = (64 + kk * 32 + g * 8) ^ (l15 * 8);
    }
    const int vrow = l15 * 64;
    const int voff[2] = { (g * 8) ^ ((l15 & 7) * 8), (32 + g * 8) ^ ((l15 & 7) * 8) };

    // Prologue: prefetch tile 0 into regs.
    bf16x8 kr[4], vr[2];
    #pragma unroll
    for (int p = 0; p < 4; ++p)
        kr[p] = *(const bf16x8*)&ksrc[(size_t)(p * 16) * 2048];
    #pragma unroll
    for (int p = 0; p < 2; ++p)
        vr[p] = *(const bf16x8*)&vsrc[(size_t)p * 32 * SEQ];

    int cur = 0;
    for (int kv = 0; kv < SEQ / 64; ++kv) {
        // Write prefetched tile into buf[cur]; lgkmcnt-only barrier orders
        // buffer reuse without draining the global prefetch queue.
        const int kb = cur * 8192, vb = cur * 4096;
        #pragma unroll
        for (int p = 0; p < 4; ++p)
            *(bf16x8*)&Ks[kb + p * 2048 + kdst] = kr[p];
        #pragma unroll
        for (int p = 0; p < 2; ++p)
            *(bf16x8*)&Vs[vb + p * 2048 + vdst] = vr[p];
        barrier_lgkm();
        if (kv + 1 < SEQ / 64) {
            const int j0n = (kv + 1) * 64;
            #pragma unroll
            for (int p = 0; p < 4; ++p)
                kr[p] = *(const bf16x8*)&ksrc[(size_t)(j0n + p * 16) * 2048];
            #pragma unroll
            for (int p = 0; p < 2; ++p)
                vr[p] = *(const bf16x8*)&vsrc[(size_t)p * 32 * SEQ + j0n];
        }

        // QK^T (swapped, bf16x3): each K fragment read feeds all 4 q-sets.
        f32x4 s[4][4] = {};
        __builtin_amdgcn_s_setprio(1);
        #pragma unroll
        for (int jt = 0; jt < 4; ++jt) {
            #pragma unroll
            for (int kk = 0; kk < 2; ++kk) {
                const bf16x8 khf = *(const bf16x8*)&Ks[kb + jt * 2048 + krow + koff[kk][0]];
                const bf16x8 klf = *(const bf16x8*)&Ks[kb + jt * 2048 + krow + koff[kk][1]];
                #pragma unroll
                for (int qs = 0; qs < 4; ++qs) {
                    s[qs][jt] = MFMA16(khf, qh[qs][kk], s[qs][jt]);
                    s[qs][jt] = MFMA16(khf, ql[qs][kk], s[qs][jt]);
                    s[qs][jt] = MFMA16(klf, qh[qs][kk], s[qs][jt]);
                }
            }
        }
        __builtin_amdgcn_s_setprio(0);

        // Online softmax (log2 domain, defer-max) + packed P, per q-set.
        bf16x8 pav[4][2];
        #pragma unroll
        for (int qs = 0; qs < 4; ++qs) {
            const f32x4* sq = s[qs];
            float mx = max3f(sq[0][0], sq[0][1], sq[0][2]);
            mx = max3f(mx, sq[0][3], sq[1][0]);
            mx = max3f(mx, sq[1][1], sq[1][2]);
            mx = max3f(mx, sq[1][3], sq[2][0]);
            mx = max3f(mx, sq[2][1], sq[2][2]);
            mx = max3f(mx, sq[2][3], sq[3][0]);
            mx = max3f(mx, sq[3][1], sq[3][2]);
            mx = fmaxf(mx, sq[3][3]);
            mx = fmaxf(mx, __shfl_xor(mx, 16));
            mx = fmaxf(mx, __shfl_xor(mx, 32));
            // Defer-max: rescale only if some q-row's max grew past m_run+8.
            if (!__all(mx - m_run[qs] <= 8.f)) {
                const float mnew = fmaxf(m_run[qs], mx);
                const float corr = __builtin_amdgcn_exp2f(m_run[qs] - mnew);
                m_run[qs] = mnew;
                l_run[qs] *= corr;
                const float cr0 = __shfl(corr, g * 4 + 0);
                const float cr1 = __shfl(corr, g * 4 + 1);
                const float cr2 = __shfl(corr, g * 4 + 2);
                const float cr3 = __shfl(corr, g * 4 + 3);
                #pragma unroll
                for (int nt = 0; nt < 4; ++nt) {
                    o[qs][nt][0] *= cr0; o[qs][nt][1] *= cr1;
                    o[qs][nt][2] *= cr2; o[qs][nt][3] *= cr3;
                }
            }
            float sm = 0.f;
            #pragma unroll
            for (int jt = 0; jt < 4; ++jt)
                #pragma unroll
                for (int r = 0; r < 4; ++r) {
                    const float e = __builtin_amdgcn_exp2f(s[qs][jt][r] - m_run[qs]);
                    s[qs][jt][r] = e; sm += e;
                }
            sm += __shfl_xor(sm, 16);
            sm += __shfl_xor(sm, 32);
            l_run[qs] += sm;

            #pragma unroll
            for (int t = 0; t < 2; ++t) {
                union { uint2 u[2]; bf16x8 v; } P;
                P.u[0] = make_uint2(cvt_pk_bf16(s[qs][2 * t][0],     s[qs][2 * t][1]),
                                    cvt_pk_bf16(s[qs][2 * t][2],     s[qs][2 * t][3]));
                P.u[1] = make_uint2(cvt_pk_bf16(s[qs][2 * t + 1][0], s[qs][2 * t + 1][1]),
                                    cvt_pk_bf16(s[qs][2 * t + 1][2], s[qs][2 * t + 1][3]));
                pav[qs][t] = P.v;
            }
        }

        // PV: one b128 V read per (t,nt), shared across all 4 q-sets.
        __builtin_amdgcn_s_setprio(1);
        #pragma unroll
        for (int t = 0; t < 2; ++t)
            #pragma unroll
            for (int nt = 0; nt < 4; ++nt) {
                const bf16x8 vbv = *(const bf16x8*)&Vs[vb + nt * 1024 + vrow + voff[t]];
                #pragma unroll
                for (int qs = 0; qs < 4; ++qs)
                    o[qs][nt] = MFMA16(pav[qs][t], vbv, o[qs][nt]);
            }
        __builtin_amdgcn_s_setprio(0);
        cur ^= 1;
    }

    // Epilogue: normalize by 1/l per O-row and store PACKED hi/lo into
    // ao_hl[ktile][M][64] with the (M&7) granule swizzle baked in.
    #pragma unroll
    for (int qs = 0; qs < 4; ++qs) {
        const float il = 1.f / l_run[qs];
        const float nr0 = __shfl(il, g * 4 + 0);
        const float nr1 = __shfl(il, g * 4 + 1);
        const float nr2 = __shfl(il, g * 4 + 2);
        const float nr3 = __shfl(il, g * 4 + 3);
        const float nr[4] = {nr0, nr1, nr2, nr3};
        #pragma unroll
        for (int nt = 0; nt < 4; ++nt) {
            const int k  = h * DHEAD + nt * 16 + l15;
            const int t  = k >> 5;
            const int kk = k & 31;
            const int G  = kk >> 3;   // 0..3
            const int e  = kk & 7;
            #pragma unroll
            for (int r = 0; r < 4; ++r) {
                const int M  = b * SEQ + q0 + qs * 16 + g * 4 + r;
                const int s7 = M & 7;
                unsigned short* dp = ao_hl + ((size_t)t * MTOT + M) * 64;
                const float v = o[qs][nt][r] * nr[r];
                const unsigned u = fau(v);
                const float res = v - __uint_as_float(u & 0xffff0000u);
                dp[((G ^ s7) << 3) + e]       = (unsigned short)(u >> 16);
                dp[(((G + 4) ^ s7) << 3) + e] = (unsigned short)(fau(res) >> 16);
            }
        }
    }
}

// ---------------------------------------------------------------------------
extern "C" void kernel_launch(void* const* d_in, const int* in_sizes, int n_in,
                              void* d_out, int out_size, void* d_ws, size_t ws_size,
                              hipStream_t stream)
{
    const float* x     = (const float*)d_in[0];  // [4,2048,1024]
    const float* w_qkv = (const float*)d_in[1];  // [1024,3072]
    const float* w_out = (const float*)d_in[2];  // [1024,1024]
    const float* b_out = (const float*)d_in[3];  // [1024]
    float* out = (float*)d_out;                  // [4,2048,1024]

    // Workspace (exactly 128 MiB):
    //   q_hl 32M | k_hl 32M | vt 16M | xa_hl 32M (x pack, reused as ao pack)
    //   | wq_hl 12M | wo_hl 4M
    unsigned short* q_hl  = (unsigned short*)d_ws;
    unsigned short* k_hl  = q_hl  + (size_t)MTOT * 2048;
    unsigned short* vt    = k_hl  + (size_t)MTOT * 2048;
    unsigned short* xa_hl = vt    + (size_t)BATCH * INNER * SEQ;
    unsigned short* wq_hl = xa_hl + (size_t)32 * MTOT * 64;
    unsigned short* wo_hl = wq_hl + (size_t)32 * QKV_N * 64;

    pack_rows_hl<<<dim3(MTOT / 256, 32), 256, 0, stream>>>(x, xa_hl, MTOT, DIM);
    pack_cols_hl<<<dim3(QKV_N / 256, 32), 256, 0, stream>>>(w_qkv, wq_hl, QKV_N);
    pack_cols_hl<<<dim3(INNER / 256, 32), 256, 0, stream>>>(w_out, wo_hl, INNER);

    // 256x128 tile, 512 threads: grid (24, 32) = 768 blocks = exactly 3/CU.
    gemm_qkv_pk<<<dim3(QKV_N / 128, MTOT / 256), 512, 0, stream>>>(
        xa_hl, wq_hl, q_hl, k_hl, vt);

    // attn overwrites xa_hl (x pack no longer needed) with the packed output.
    // Grid order (h, qb, b): flat%8 = h%8 -> same-(b,h) q-blocks share an XCD.
    attn_mfma<<<dim3(HEADS, SEQ / 256, BATCH), 256, 0, stream>>>(
        q_hl, k_hl, vt, xa_hl);

    // 256 blocks = exactly 1/CU.
    gemm_out_pk<<<dim3(INNER / 128, MTOT / 256), 512, 0, stream>>>(
        xa_hl, wo_hl, b_out, out);
}